// Round 2
// baseline (30268.661 us; speedup 1.0000x reference)
//
#include <hip/hip_runtime.h>
#include <math.h>

#define NB 16
#define NT 512
#define NE 1024
#define ND 1024
#define NA 1024
#define NO 10000
#define NL 128
#define NOL 129
#define NROWS (NB*NOL)   /* 2064 */
#define TOK_SOS 9999
#define TOK_EOS 9999
#define NBLK 256

typedef unsigned short u16;
typedef __bf16 bf16x8 __attribute__((ext_vector_type(8)));
typedef float f32x4 __attribute__((ext_vector_type(4)));
typedef unsigned short u16x8 __attribute__((ext_vector_type(8)));
typedef unsigned short u16x4 __attribute__((ext_vector_type(4)));

__device__ __forceinline__ float sigf(float x){ return 1.0f/(1.0f+expf(-x)); }
__device__ __forceinline__ float b2f(u16 s){
  union { unsigned int i; float f; } u; u.i = ((unsigned int)s) << 16; return u.f;
}
__device__ __forceinline__ u16 f2b(float f){
  union { float f; unsigned int i; } u; u.f = f;
  unsigned int r = u.i + 0x7FFFu + ((u.i >> 16) & 1u);
  return (u16)(r >> 16);
}

// ---------------- zero (uint4 granularity) ----------------
__global__ void zero4_kernel(uint4* __restrict__ p, int n){
  int i = blockIdx.x*256 + threadIdx.x;
  if (i < n) p[i] = make_uint4(0,0,0,0);
}

// ---------------- f32 [4096][ld] (col slice) -> bf16 [4096][1024] ----------------
__global__ __launch_bounds__(256) void cvt_nk_kernel(
    const float* __restrict__ src, int ld, int off, u16* __restrict__ dst){
  int i = (blockIdx.x*256 + threadIdx.x)*4;   // over 4096*1024
  int row = i >> 10, col = i & 1023;
  float4 v = *(const float4*)(src + (size_t)row*ld + off + col);
  u16x4 o = { f2b(v.x), f2b(v.y), f2b(v.z), f2b(v.w) };
  *(u16x4*)(dst + i) = o;
}

// ---------------- Wdec [K=1024][N=1024] f32 -> MFMA B-fragment tiles bf16 ----------------
// dst[((nt*32+kt)*64 + lane)*8 + j] = Wdec[kt*32 + (lane>>4)*8 + j][nt*16 + (lane&15)]
__global__ __launch_bounds__(256) void wdec_swz_kernel(
    const float* __restrict__ W, u16* __restrict__ dst){
  int o = blockIdx.x*256 + threadIdx.x;     // 0..2^20-1
  int j = o & 7, ln = (o>>3) & 63, tile = o >> 9;
  int kt = tile & 31, nt = tile >> 5;
  int k = kt*32 + (ln>>4)*8 + j;
  int n = nt*16 + (ln & 15);
  dst[o] = f2b(W[(size_t)k*1024 + n]);
}

// ---------------- hpad masked f32 -> bf16 ----------------
__global__ __launch_bounds__(256) void hpad_cvt_kernel(
    const float* __restrict__ hpad, const int* __restrict__ hlen, u16* __restrict__ dst){
  int i = (blockIdx.x*256 + threadIdx.x)*4;  // over 16*512*1024
  int bt = i >> 10;
  int b = bt >> 9, tt = bt & 511;
  float4 v = *(const float4*)(hpad + (size_t)i);
  float m = (tt < hlen[b]) ? 1.0f : 0.0f;
  u16x4 o = { f2b(v.x*m), f2b(v.y*m), f2b(v.z*m), f2b(v.w*m) };
  *(u16x4*)(dst + i) = o;
}

// ---------------- bias1 = bih1 + bhh1 ----------------
__global__ void bias_add_kernel(const float* __restrict__ a, const float* __restrict__ b,
                                float* __restrict__ o){
  int i = blockIdx.x*256 + threadIdx.x;
  if (i < 4096) o[i] = a[i] + b[i];
}

// ---------------- pre_enc = tanh(mask(hpad) @ Wenc) -> bf16 [8192][1024] ----------------
__global__ __launch_bounds__(256) void preenc_kernel(
    const float* __restrict__ hpad, const int* __restrict__ hlen,
    const float* __restrict__ Wenc, u16* __restrict__ pre){
  __shared__ float As[32][68];
  __shared__ float Bs[32][68];
  const int m0 = blockIdx.x*64, n0 = blockIdx.y*64;
  const int tid = threadIdx.x;
  const int ty = tid>>4, tx = tid&15;
  const int ar = tid>>2, akg = (tid&3)*8;
  const int am = m0 + ar;
  const bool arow_on = ((am & 511) < hlen[am >> 9]);
  const int bk = tid>>3, bng = (tid&7)*8;
  float acc[4][4] = {{0.0f}};
  for (int k0=0; k0<NE; k0+=32){
    float4 a0 = make_float4(0,0,0,0), a1 = make_float4(0,0,0,0);
    if (arow_on){
      const float4* s = (const float4*)(hpad + (size_t)am*NE + k0 + akg);
      a0 = s[0]; a1 = s[1];
    }
    As[akg+0][ar]=a0.x; As[akg+1][ar]=a0.y; As[akg+2][ar]=a0.z; As[akg+3][ar]=a0.w;
    As[akg+4][ar]=a1.x; As[akg+5][ar]=a1.y; As[akg+6][ar]=a1.z; As[akg+7][ar]=a1.w;
    {
      const float4* s = (const float4*)(Wenc + (size_t)(k0+bk)*NA + n0 + bng);
      *(float4*)&Bs[bk][bng]   = s[0];
      *(float4*)&Bs[bk][bng+4] = s[1];
    }
    __syncthreads();
    #pragma unroll
    for (int kk=0; kk<32; ++kk){
      float4 a = *(const float4*)&As[kk][ty*4];
      float4 b = *(const float4*)&Bs[kk][tx*4];
      float av[4]={a.x,a.y,a.z,a.w}, bv[4]={b.x,b.y,b.z,b.w};
      #pragma unroll
      for (int i=0;i<4;++i)
        #pragma unroll
        for (int j=0;j<4;++j) acc[i][j] += av[i]*bv[j];
    }
    __syncthreads();
  }
  #pragma unroll
  for (int i=0;i<4;++i){
    u16x4 o = { f2b(tanhf(acc[i][0])), f2b(tanhf(acc[i][1])),
                f2b(tanhf(acc[i][2])), f2b(tanhf(acc[i][3])) };
    *(u16x4*)(pre + (size_t)(m0+ty*4+i)*NA + n0 + tx*4) = o;
  }
}

// ---------------- g_ey = embed[ys_in] @ Wih0[:, 0:1024]^T + bih0 + bhh0 -> bf16 [2064][4096] ----
__global__ __launch_bounds__(256) void gey_kernel(
    const int* __restrict__ ys, const float* __restrict__ embed,
    const float* __restrict__ Wih0, const float* __restrict__ bih0,
    const float* __restrict__ bhh0, u16* __restrict__ gey){
  __shared__ float As[32][68];
  __shared__ float Bs[32][68];
  const int m0 = blockIdx.x*64, n0 = blockIdx.y*64;
  const int tid = threadIdx.x;
  const int ty = tid>>4, tx = tid&15;
  const int ar = tid>>2, akg = (tid&3)*8;
  const int am = m0 + ar;
  const bool arow_on = (am < NROWS);
  int tok = 0;
  if (arow_on){
    int b = am / NOL, l = am - b*NOL;
    tok = (l==0) ? TOK_SOS : ys[b*NL + l - 1];
  }
  const int bj = tid>>2, bkg = (tid&3)*8;
  float acc[4][4] = {{0.0f}};
  for (int k0=0; k0<ND; k0+=32){
    float4 a0 = make_float4(0,0,0,0), a1 = make_float4(0,0,0,0);
    if (arow_on){
      const float4* s = (const float4*)(embed + (size_t)tok*ND + k0 + akg);
      a0 = s[0]; a1 = s[1];
    }
    As[akg+0][ar]=a0.x; As[akg+1][ar]=a0.y; As[akg+2][ar]=a0.z; As[akg+3][ar]=a0.w;
    As[akg+4][ar]=a1.x; As[akg+5][ar]=a1.y; As[akg+6][ar]=a1.z; As[akg+7][ar]=a1.w;
    {
      const float4* s = (const float4*)(Wih0 + (size_t)(n0+bj)*2048 + k0 + bkg);
      float4 b0 = s[0], b1 = s[1];
      Bs[bkg+0][bj]=b0.x; Bs[bkg+1][bj]=b0.y; Bs[bkg+2][bj]=b0.z; Bs[bkg+3][bj]=b0.w;
      Bs[bkg+4][bj]=b1.x; Bs[bkg+5][bj]=b1.y; Bs[bkg+6][bj]=b1.z; Bs[bkg+7][bj]=b1.w;
    }
    __syncthreads();
    #pragma unroll
    for (int kk=0; kk<32; ++kk){
      float4 a = *(const float4*)&As[kk][ty*4];
      float4 b = *(const float4*)&Bs[kk][tx*4];
      float av[4]={a.x,a.y,a.z,a.w}, bv[4]={b.x,b.y,b.z,b.w};
      #pragma unroll
      for (int i=0;i<4;++i)
        #pragma unroll
        for (int j=0;j<4;++j) acc[i][j] += av[i]*bv[j];
    }
    __syncthreads();
  }
  #pragma unroll
  for (int i=0;i<4;++i){
    int row = m0+ty*4+i;
    if (row < NROWS){
      int col = n0 + tx*4;
      u16x4 o = { f2b(acc[i][0]+bih0[col+0]+bhh0[col+0]),
                  f2b(acc[i][1]+bih0[col+1]+bhh0[col+1]),
                  f2b(acc[i][2]+bih0[col+2]+bhh0[col+2]),
                  f2b(acc[i][3]+bih0[col+3]+bhh0[col+3]) };
      *(u16x4*)(gey + (size_t)row*4096 + col) = o;
    }
  }
}

// ---------------- device-scope slot barrier ----------------
__device__ __forceinline__ void gbar(int* bars, int slot){
  __syncthreads();
  if (threadIdx.x == 0){
    __threadfence();
    __hip_atomic_fetch_add(&bars[slot], 1, __ATOMIC_ACQ_REL, __HIP_MEMORY_SCOPE_AGENT);
    while (__hip_atomic_load(&bars[slot], __ATOMIC_ACQUIRE, __HIP_MEMORY_SCOPE_AGENT) < NBLK){
      __builtin_amdgcn_s_sleep(2);
    }
    __threadfence();
  }
  __syncthreads();
}

// ---------------- persistent sequential kernel: 129 decoder steps ----------------
// grid = 256 blocks x 256 threads (1 block/CU => co-resident)
__global__ __launch_bounds__(256, 1) void seq_kernel(
    const u16* __restrict__ pre,   // [8192][1024] bf16
    const u16* __restrict__ hpad,  // [16][512][1024] bf16 masked
    const u16* __restrict__ w0c,   // [4096][1024] Wih0[:,1024:] bf16
    const u16* __restrict__ wh0,   // [4096][1024]
    const u16* __restrict__ w1c,   // [4096][1024] Wih1
    const u16* __restrict__ wh1,   // [4096][1024]
    const u16* __restrict__ wdec,  // swizzled tiles
    const u16* __restrict__ gey,   // [2064][4096] bf16
    const float* __restrict__ bias1, // [4096]
    float* dqf,                    // [16][1024] f32
    float* esc,                    // [16][512] f32 (already x2 scaled)
    u16* attc,                     // [16][1024] bf16
    u16* z0bf, u16* z1bf,          // [2][16][1024] bf16 ping-pong
    float* c0, float* c1,          // [16][1024] f32
    float* zall,                   // [2064][1024] f32
    int* bars)
{
  const int wg = blockIdx.x, tid = threadIdx.x;
  const int lane = tid & 63, wv = tid >> 6;
  const int r = lane & 15, q = lane >> 4;
  __shared__ float sw[512];
  __shared__ float spart[4][64];
  __shared__ float sred[256];
  __shared__ float gex[4][16][16];
  int slot = 0;

  for (int t = 0; t <= NOL; ++t){
    const int cur = t & 1, prv = cur ^ 1;

    // ======== Phase A: dq(t) [wg<64]  ||  gemm1+cell1(t-1) [64<=wg<128] ========
    if (wg < 64){
      if (t < NOL){
        f32x4 acc = {0.f,0.f,0.f,0.f};
        const u16* Ar = z0bf + prv*16384 + r*1024 + q*8;
        const u16* Bw = wdec + (size_t)wg*16384 + lane*8;
        #pragma unroll
        for (int i = 0; i < 8; ++i){
          int kt = wv*8 + i;
          bf16x8 a = *(const bf16x8*)(Ar + kt*32);
          bf16x8 b = *(const bf16x8*)(Bw + (size_t)kt*512);
          acc = __builtin_amdgcn_mfma_f32_16x16x32_bf16(a, b, acc, 0, 0, 0);
        }
        #pragma unroll
        for (int rr = 0; rr < 4; ++rr) gex[wv][q*4+rr][r] = acc[rr];
        __syncthreads();
        {
          int b = tid >> 4, j = tid & 15;
          float s = gex[0][b][j] + gex[1][b][j] + gex[2][b][j] + gex[3][b][j];
          dqf[b*1024 + wg*16 + j] = tanhf(s);
        }
      }
    } else if (wg < 128){
      if (t >= 1){
        const int s = t - 1;
        const int dt = wg - 64;
        const int n0 = wv*1024 + dt*16;
        f32x4 acc = {0.f,0.f,0.f,0.f};
        const u16* Ar0 = z0bf + prv*16384 + r*1024 + q*8;
        const u16* Br0 = w1c + (size_t)(n0 + r)*1024 + q*8;
        #pragma unroll 8
        for (int kt = 0; kt < 32; ++kt){
          bf16x8 a = *(const bf16x8*)(Ar0 + kt*32);
          bf16x8 b = *(const bf16x8*)(Br0 + kt*32);
          acc = __builtin_amdgcn_mfma_f32_16x16x32_bf16(a, b, acc, 0, 0, 0);
        }
        const u16* Ar1 = z1bf + cur*16384 + r*1024 + q*8;
        const u16* Br1 = wh1 + (size_t)(n0 + r)*1024 + q*8;
        #pragma unroll 8
        for (int kt = 0; kt < 32; ++kt){
          bf16x8 a = *(const bf16x8*)(Ar1 + kt*32);
          bf16x8 b = *(const bf16x8*)(Br1 + kt*32);
          acc = __builtin_amdgcn_mfma_f32_16x16x32_bf16(a, b, acc, 0, 0, 0);
        }
        #pragma unroll
        for (int rr = 0; rr < 4; ++rr) gex[wv][q*4+rr][r] = acc[rr];
        __syncthreads();
        {
          int b = tid >> 4, dj = tid & 15, d = dt*16 + dj, idx = b*1024 + d;
          float gi = gex[0][b][dj] + bias1[d];
          float gf = gex[1][b][dj] + bias1[1024 + d];
          float gg = gex[2][b][dj] + bias1[2048 + d];
          float go = gex[3][b][dj] + bias1[3072 + d];
          float cn = sigf(gf)*c1[idx] + sigf(gi)*tanhf(gg);
          float zn = sigf(go)*tanhf(cn);
          c1[idx] = cn;
          z1bf[prv*16384 + idx] = f2b(zn);
          zall[((size_t)b*NOL + s)*1024 + d] = zn;
        }
      }
    }
    gbar(bars, slot++);
    if (t == NOL) break;

    // ======== Phase B: escore(t) = 2 * pre . dq ========
    {
      const int wid = wg*4 + wv;
      const int rbase = wid*8;            // 8 rows per wave, same b
      const int b = rbase >> 9;
      float qv[16];
      const float* dqb = dqf + b*1024 + lane*16;
      *(float4*)(qv+0)  = *(const float4*)(dqb+0);
      *(float4*)(qv+4)  = *(const float4*)(dqb+4);
      *(float4*)(qv+8)  = *(const float4*)(dqb+8);
      *(float4*)(qv+12) = *(const float4*)(dqb+12);
      #pragma unroll
      for (int rr = 0; rr < 8; ++rr){
        const u16* pr = pre + (size_t)(rbase+rr)*1024 + lane*16;
        u16x8 p0 = *(const u16x8*)(pr);
        u16x8 p1 = *(const u16x8*)(pr+8);
        float acc = 0.f;
        #pragma unroll
        for (int j = 0; j < 8; ++j){
          acc += b2f(p0[j])*qv[j];
          acc += b2f(p1[j])*qv[8+j];
        }
        #pragma unroll
        for (int off = 32; off > 0; off >>= 1) acc += __shfl_xor(acc, off, 64);
        if (lane == 0) esc[rbase+rr] = 2.0f*acc;
      }
    }
    gbar(bars, slot++);

    // ======== Phase C: softmax + att_c ========
    {
      const int b = wg >> 4, ec = wg & 15;
      const float* eb = esc + b*512;
      float e0 = eb[tid], e1 = eb[tid+256];
      sred[tid] = fmaxf(e0, e1);
      __syncthreads();
      #pragma unroll
      for (int s2 = 128; s2 > 0; s2 >>= 1){
        if (tid < s2) sred[tid] = fmaxf(sred[tid], sred[tid+s2]);
        __syncthreads();
      }
      float mx = sred[0];
      __syncthreads();
      float p0 = expf(e0 - mx), p1 = expf(e1 - mx);
      sred[tid] = p0 + p1;
      __syncthreads();
      #pragma unroll
      for (int s2 = 128; s2 > 0; s2 >>= 1){
        if (tid < s2) sred[tid] += sred[tid+s2];
        __syncthreads();
      }
      float inv = 1.0f/sred[0];
      sw[tid] = p0*inv; sw[tid+256] = p1*inv;
      __syncthreads();
      const int e = ec*64 + lane;
      const u16* hp = hpad + ((size_t)b*512 + wv*128)*1024 + e;
      float acc = 0.f;
      #pragma unroll 8
      for (int tt = 0; tt < 128; ++tt) acc += sw[wv*128+tt] * b2f(hp[(size_t)tt*1024]);
      spart[wv][lane] = acc;
      __syncthreads();
      if (tid < 64){
        float s2 = spart[0][tid]+spart[1][tid]+spart[2][tid]+spart[3][tid];
        attc[b*1024 + ec*64 + tid] = f2b(s2);
      }
    }
    gbar(bars, slot++);

    // ======== Phase D: gemm0 + cell0(t) [wg<64] ========
    if (wg < 64){
      const int n0 = wv*1024 + wg*16;
      f32x4 acc = {0.f,0.f,0.f,0.f};
      const u16* Ar0 = attc + r*1024 + q*8;
      const u16* Br0 = w0c + (size_t)(n0 + r)*1024 + q*8;
      #pragma unroll 8
      for (int kt = 0; kt < 32; ++kt){
        bf16x8 a = *(const bf16x8*)(Ar0 + kt*32);
        bf16x8 b = *(const bf16x8*)(Br0 + kt*32);
        acc = __builtin_amdgcn_mfma_f32_16x16x32_bf16(a, b, acc, 0, 0, 0);
      }
      const u16* Ar1 = z0bf + prv*16384 + r*1024 + q*8;
      const u16* Br1 = wh0 + (size_t)(n0 + r)*1024 + q*8;
      #pragma unroll 8
      for (int kt = 0; kt < 32; ++kt){
        bf16x8 a = *(const bf16x8*)(Ar1 + kt*32);
        bf16x8 b = *(const bf16x8*)(Br1 + kt*32);
        acc = __builtin_amdgcn_mfma_f32_16x16x32_bf16(a, b, acc, 0, 0, 0);
      }
      #pragma unroll
      for (int rr = 0; rr < 4; ++rr) gex[wv][q*4+rr][r] = acc[rr];
      __syncthreads();
      {
        int b = tid >> 4, dj = tid & 15, d = wg*16 + dj, idx = b*1024 + d;
        const u16* gr = gey + ((size_t)b*NOL + t)*4096 + d;
        float gi = gex[0][b][dj] + b2f(gr[0]);
        float gf = gex[1][b][dj] + b2f(gr[1024]);
        float gg = gex[2][b][dj] + b2f(gr[2048]);
        float go = gex[3][b][dj] + b2f(gr[3072]);
        float cn = sigf(gf)*c0[idx] + sigf(gi)*tanhf(gg);
        float zn = sigf(go)*tanhf(cn);
        c0[idx] = cn;
        z0bf[cur*16384 + idx] = f2b(zn);
      }
    }
    gbar(bars, slot++);
  }
}

// ---------------- logits = z_all @ Wout + bout -> bf16 [2064][10000] ----------------
__global__ __launch_bounds__(256) void logits_kernel(
    const float* __restrict__ zall, const float* __restrict__ Wout,
    const float* __restrict__ bout, u16* __restrict__ logits){
  __shared__ float As[32][68];
  __shared__ float Bs[32][68];
  const int m0 = blockIdx.x*64, n0 = blockIdx.y*64;
  const int tid = threadIdx.x;
  const int ty = tid>>4, tx = tid&15;
  const int ar = tid>>2, akg = (tid&3)*8;
  const int am = m0 + ar;
  const bool arow_on = (am < NROWS);
  const int bk = tid>>3, bng = (tid&7)*8;
  const bool nfull = (n0 + 64 <= NO);
  float acc[4][4] = {{0.0f}};
  for (int k0=0; k0<ND; k0+=32){
    float4 a0 = make_float4(0,0,0,0), a1 = make_float4(0,0,0,0);
    if (arow_on){
      const float4* s = (const float4*)(zall + (size_t)am*ND + k0 + akg);
      a0 = s[0]; a1 = s[1];
    }
    As[akg+0][ar]=a0.x; As[akg+1][ar]=a0.y; As[akg+2][ar]=a0.z; As[akg+3][ar]=a0.w;
    As[akg+4][ar]=a1.x; As[akg+5][ar]=a1.y; As[akg+6][ar]=a1.z; As[akg+7][ar]=a1.w;
    if (nfull){
      const float4* s = (const float4*)(Wout + (size_t)(k0+bk)*NO + n0 + bng);
      *(float4*)&Bs[bk][bng]   = s[0];
      *(float4*)&Bs[bk][bng+4] = s[1];
    } else {
      #pragma unroll
      for (int i=0;i<8;++i){
        int n = n0 + bng + i;
        Bs[bk][bng+i] = (n < NO) ? Wout[(size_t)(k0+bk)*NO + n] : 0.0f;
      }
    }
    __syncthreads();
    #pragma unroll
    for (int kk=0; kk<32; ++kk){
      float4 a = *(const float4*)&As[kk][ty*4];
      float4 b = *(const float4*)&Bs[kk][tx*4];
      float av[4]={a.x,a.y,a.z,a.w}, bv[4]={b.x,b.y,b.z,b.w};
      #pragma unroll
      for (int i=0;i<4;++i)
        #pragma unroll
        for (int j=0;j<4;++j) acc[i][j] += av[i]*bv[j];
    }
    __syncthreads();
  }
  #pragma unroll
  for (int i=0;i<4;++i){
    int row = m0+ty*4+i;
    if (row < NROWS){
      #pragma unroll
      for (int j=0;j<4;++j){
        int col = n0 + tx*4 + j;
        if (col < NO) logits[(size_t)row*NO + col] = f2b(acc[i][j] + bout[col]);
      }
    }
  }
}

// ---------------- per-row log_softmax + NLL + argmax (bf16 logits) ----------------
__global__ __launch_bounds__(256) void loss_kernel(
    const u16* __restrict__ logits, const int* __restrict__ ys, float* __restrict__ accum){
  int row = blockIdx.x;
  int tid = threadIdx.x;
  const u16* lr = logits + (size_t)row * NO;
  __shared__ float sv[256];
  __shared__ int   si[256];
  float mx = -INFINITY; int mi = 0;
  for (int n = tid; n < NO; n += 256){
    float v = b2f(lr[n]);
    if (v > mx){ mx = v; mi = n; }
  }
  sv[tid] = mx; si[tid] = mi;
  __syncthreads();
  for (int s=128; s>0; s>>=1){
    if (tid < s){
      if (sv[tid+s] > sv[tid] || (sv[tid+s]==sv[tid] && si[tid+s] < si[tid])){
        sv[tid] = sv[tid+s]; si[tid] = si[tid+s];
      }
    }
    __syncthreads();
  }
  float gmx = sv[0]; int gmi = si[0];
  __syncthreads();
  float ps = 0.0f;
  for (int n = tid; n < NO; n += 256) ps += expf(b2f(lr[n])-gmx);
  sv[tid] = ps;
  __syncthreads();
  for (int s=128; s>0; s>>=1){ if (tid<s) sv[tid] += sv[tid+s]; __syncthreads(); }
  if (tid==0){
    int b = row / NOL, l = row - b*NOL;
    int label = (l < NL) ? ys[b*NL + l] : TOK_EOS;
    float lse = gmx + logf(sv[0]);
    float nll = lse - b2f(lr[label]);
    atomicAdd(&accum[0], nll);
    atomicAdd(&accum[1], (gmi==label) ? 1.0f : 0.0f);
  }
}

__global__ void finalize_kernel(const float* __restrict__ accum, float* __restrict__ out){
  out[0] = accum[0] / (float)NROWS * (float)(NOL-1);
  out[1] = accum[1] / (float)NROWS;
}

extern "C" void kernel_launch(void* const* d_in, const int* in_sizes, int n_in,
                              void* d_out, int out_size, void* d_ws, size_t ws_size,
                              hipStream_t stream){
  const float* hpad  = (const float*)d_in[0];
  const int*   hlen  = (const int*)  d_in[1];
  const int*   ys    = (const int*)  d_in[2];
  const float* embed = (const float*)d_in[3];
  const float* Wenc  = (const float*)d_in[4];
  const float* Wdec  = (const float*)d_in[5];
  const float* Wih0  = (const float*)d_in[6];
  const float* Whh0  = (const float*)d_in[7];
  const float* bih0  = (const float*)d_in[8];
  const float* bhh0  = (const float*)d_in[9];
  const float* Wih1  = (const float*)d_in[10];
  const float* Whh1  = (const float*)d_in[11];
  const float* bih1  = (const float*)d_in[12];
  const float* bhh1  = (const float*)d_in[13];
  const float* Wout  = (const float*)d_in[14];
  const float* bout  = (const float*)d_in[15];
  float* out = (float*)d_out;

  char* ws = (char*)d_ws;
  size_t cur = 0;
  auto alloc = [&](size_t bytes) -> char* {
    char* p = ws + cur;
    cur += (bytes + 255) & ~(size_t)255;
    return p;
  };
  u16*   pre_bf   = (u16*)  alloc(16777216);   // [8192][1024]
  u16*   hpad_bf  = (u16*)  alloc(16777216);   // [16][512][1024]
  u16*   w0c      = (u16*)  alloc(8388608);    // Wih0[:,1024:]
  u16*   wh0      = (u16*)  alloc(8388608);
  u16*   w1c      = (u16*)  alloc(8388608);
  u16*   wh1      = (u16*)  alloc(8388608);
  u16*   wdec_sw  = (u16*)  alloc(2097152);
  u16*   gey      = (u16*)  alloc(16908288);   // [2064][4096]
  float* zall     = (float*)alloc(8454144);    // [2064][1024]
  u16*   logits   = (u16*)  alloc(41280000);   // [2064][10000]
  float* dqf      = (float*)alloc(65536);
  float* esc      = (float*)alloc(32768);
  u16*   attc     = (u16*)  alloc(32768);
  float* bias1    = (float*)alloc(16384);
  // ---- zeroed region (contiguous) ----
  int*   bars     = (int*)  alloc(2560);       // 640 barrier slots
  u16*   z0bf     = (u16*)  alloc(65536);      // [2][16][1024]
  u16*   z1bf     = (u16*)  alloc(65536);
  float* c0       = (float*)alloc(65536);
  float* c1       = (float*)alloc(65536);
  float* accum    = (float*)alloc(128);
  // zero bytes = 2560 + 4*65536 + 128 = 264832 -> 16552 uint4
  zero4_kernel<<<65, 256, 0, stream>>>((uint4*)bars, 16552);

  cvt_nk_kernel<<<4096, 256, 0, stream>>>(Wih0, 2048, 1024, w0c);
  cvt_nk_kernel<<<4096, 256, 0, stream>>>(Whh0, 1024, 0, wh0);
  cvt_nk_kernel<<<4096, 256, 0, stream>>>(Wih1, 1024, 0, w1c);
  cvt_nk_kernel<<<4096, 256, 0, stream>>>(Whh1, 1024, 0, wh1);
  wdec_swz_kernel<<<4096, 256, 0, stream>>>(Wdec, wdec_sw);
  hpad_cvt_kernel<<<8192, 256, 0, stream>>>(hpad, hlen, hpad_bf);
  bias_add_kernel<<<16, 256, 0, stream>>>(bih1, bhh1, bias1);
  preenc_kernel<<<dim3(128,16), 256, 0, stream>>>(hpad, hlen, Wenc, pre_bf);
  gey_kernel<<<dim3(33,64), 256, 0, stream>>>(ys, embed, Wih0, bih0, bhh0, gey);

  seq_kernel<<<NBLK, 256, 0, stream>>>(pre_bf, hpad_bf, w0c, wh0, w1c, wh1,
                                       wdec_sw, gey, bias1, dqf, esc, attc,
                                       z0bf, z1bf, c0, c1, zall, bars);

  logits_kernel<<<dim3(33,157), 256, 0, stream>>>(zall, Wout, bout, logits);
  loss_kernel<<<NROWS, 256, 0, stream>>>(logits, ys, accum);
  finalize_kernel<<<1, 1, 0, stream>>>(accum, out);
}

// Round 3
// 14619.341 us; speedup vs baseline: 2.0705x; 2.0705x over previous
//
#include <hip/hip_runtime.h>
#include <math.h>

#define NB 16
#define NT 512
#define NE 1024
#define ND 1024
#define NA 1024
#define NO 10000
#define NL 128
#define NOL 129
#define NROWS (NB*NOL)   /* 2064 */
#define TOK_SOS 9999
#define TOK_EOS 9999
#define NBLK 128

typedef unsigned short u16;
typedef unsigned int u32;
typedef __bf16 bf16x8 __attribute__((ext_vector_type(8)));
typedef float f32x4 __attribute__((ext_vector_type(4)));
typedef unsigned short u16x8 __attribute__((ext_vector_type(8)));
typedef unsigned short u16x4 __attribute__((ext_vector_type(4)));

__device__ __forceinline__ float sigf(float x){ return 1.0f/(1.0f+expf(-x)); }
__device__ __forceinline__ float b2f(u16 s){
  union { u32 i; float f; } u; u.i = ((u32)s) << 16; return u.f;
}
__device__ __forceinline__ u16 f2b(float f){
  union { float f; u32 i; } u; u.f = f;
  u32 r = u.i + 0x7FFFu + ((u.i >> 16) & 1u);
  return (u16)(r >> 16);
}

// ---- coherent (cache-bypassing, relaxed) helpers: NO cache maintenance ops ----
__device__ __forceinline__ float coh_ldf(const float* p){
  return __hip_atomic_load((float*)p, __ATOMIC_RELAXED, __HIP_MEMORY_SCOPE_AGENT);
}
__device__ __forceinline__ void coh_stf(float* p, float v){
  __hip_atomic_store(p, v, __ATOMIC_RELAXED, __HIP_MEMORY_SCOPE_AGENT);
}
__device__ __forceinline__ u32 coh_ldu(const u32* p){
  return __hip_atomic_load((u32*)p, __ATOMIC_RELAXED, __HIP_MEMORY_SCOPE_AGENT);
}
__device__ __forceinline__ void coh_stu(u32* p, u32 v){
  __hip_atomic_store(p, v, __ATOMIC_RELAXED, __HIP_MEMORY_SCOPE_AGENT);
}
// load 8 bf16 (16B, aligned) via 4 coherent u32 loads -> MFMA fragment
__device__ __forceinline__ bf16x8 coh_ld8h(const u16* p){
  const u32* q = (const u32*)p;
  union { u32 u[4]; bf16x8 b; } c;
  c.u[0] = coh_ldu(q+0); c.u[1] = coh_ldu(q+1);
  c.u[2] = coh_ldu(q+2); c.u[3] = coh_ldu(q+3);
  return c.b;
}

// ---------------- zero (uint4 granularity) ----------------
__global__ void zero4_kernel(uint4* __restrict__ p, int n){
  int i = blockIdx.x*256 + threadIdx.x;
  if (i < n) p[i] = make_uint4(0,0,0,0);
}

// ---------------- f32 [4096][ld] (col slice) -> bf16 [4096][1024] ----------------
__global__ __launch_bounds__(256) void cvt_nk_kernel(
    const float* __restrict__ src, int ld, int off, u16* __restrict__ dst){
  int i = (blockIdx.x*256 + threadIdx.x)*4;   // over 4096*1024
  int row = i >> 10, col = i & 1023;
  float4 v = *(const float4*)(src + (size_t)row*ld + off + col);
  u16x4 o = { f2b(v.x), f2b(v.y), f2b(v.z), f2b(v.w) };
  *(u16x4*)(dst + i) = o;
}

// ---------------- Wdec [K=1024][N=1024] f32 -> MFMA B-fragment tiles bf16 ----------------
__global__ __launch_bounds__(256) void wdec_swz_kernel(
    const float* __restrict__ W, u16* __restrict__ dst){
  int o = blockIdx.x*256 + threadIdx.x;     // 0..2^20-1
  int j = o & 7, ln = (o>>3) & 63, tile = o >> 9;
  int kt = tile & 31, nt = tile >> 5;
  int k = kt*32 + (ln>>4)*8 + j;
  int n = nt*16 + (ln & 15);
  dst[o] = f2b(W[(size_t)k*1024 + n]);
}

// ---------------- hpad [16][512][1024] f32 -> masked bf16 transposed [16][1024][512] ----------
__global__ __launch_bounds__(256) void hpadT_kernel(
    const float* __restrict__ hpad, const int* __restrict__ hlen, u16* __restrict__ dst){
  __shared__ float tile[32][33];
  const int e0 = blockIdx.x*32, t0 = blockIdx.y*32, b = blockIdx.z;
  const int tx = threadIdx.x & 31, ty = threadIdx.x >> 5;
  const int len = hlen[b];
  #pragma unroll
  for (int k = 0; k < 4; ++k){
    int r = ty + k*8;  // t row
    tile[r][tx] = hpad[((size_t)b*512 + t0 + r)*1024 + e0 + tx];
  }
  __syncthreads();
  #pragma unroll
  for (int k = 0; k < 4; ++k){
    int el = ty + k*8;
    float m = (t0 + tx < len) ? 1.0f : 0.0f;
    dst[((size_t)b*1024 + e0 + el)*512 + t0 + tx] = f2b(tile[tx][el]*m);
  }
}

// ---------------- bias1 = bih1 + bhh1 ----------------
__global__ void bias_add_kernel(const float* __restrict__ a, const float* __restrict__ b,
                                float* __restrict__ o){
  int i = blockIdx.x*256 + threadIdx.x;
  if (i < 4096) o[i] = a[i] + b[i];
}

// ---------------- pre_enc = tanh(mask(hpad) @ Wenc) -> bf16 [8192][1024] ----------------
__global__ __launch_bounds__(256) void preenc_kernel(
    const float* __restrict__ hpad, const int* __restrict__ hlen,
    const float* __restrict__ Wenc, u16* __restrict__ pre){
  __shared__ float As[32][68];
  __shared__ float Bs[32][68];
  const int m0 = blockIdx.x*64, n0 = blockIdx.y*64;
  const int tid = threadIdx.x;
  const int ty = tid>>4, tx = tid&15;
  const int ar = tid>>2, akg = (tid&3)*8;
  const int am = m0 + ar;
  const bool arow_on = ((am & 511) < hlen[am >> 9]);
  const int bk = tid>>3, bng = (tid&7)*8;
  float acc[4][4] = {{0.0f}};
  for (int k0=0; k0<NE; k0+=32){
    float4 a0 = make_float4(0,0,0,0), a1 = make_float4(0,0,0,0);
    if (arow_on){
      const float4* s = (const float4*)(hpad + (size_t)am*NE + k0 + akg);
      a0 = s[0]; a1 = s[1];
    }
    As[akg+0][ar]=a0.x; As[akg+1][ar]=a0.y; As[akg+2][ar]=a0.z; As[akg+3][ar]=a0.w;
    As[akg+4][ar]=a1.x; As[akg+5][ar]=a1.y; As[akg+6][ar]=a1.z; As[akg+7][ar]=a1.w;
    {
      const float4* s = (const float4*)(Wenc + (size_t)(k0+bk)*NA + n0 + bng);
      *(float4*)&Bs[bk][bng]   = s[0];
      *(float4*)&Bs[bk][bng+4] = s[1];
    }
    __syncthreads();
    #pragma unroll
    for (int kk=0; kk<32; ++kk){
      float4 a = *(const float4*)&As[kk][ty*4];
      float4 b = *(const float4*)&Bs[kk][tx*4];
      float av[4]={a.x,a.y,a.z,a.w}, bv[4]={b.x,b.y,b.z,b.w};
      #pragma unroll
      for (int i=0;i<4;++i)
        #pragma unroll
        for (int j=0;j<4;++j) acc[i][j] += av[i]*bv[j];
    }
    __syncthreads();
  }
  #pragma unroll
  for (int i=0;i<4;++i){
    u16x4 o = { f2b(tanhf(acc[i][0])), f2b(tanhf(acc[i][1])),
                f2b(tanhf(acc[i][2])), f2b(tanhf(acc[i][3])) };
    *(u16x4*)(pre + (size_t)(m0+ty*4+i)*NA + n0 + tx*4) = o;
  }
}

// ---------------- g_ey = embed[ys_in] @ Wih0[:, 0:1024]^T + bih0 + bhh0 -> bf16 ----------------
__global__ __launch_bounds__(256) void gey_kernel(
    const int* __restrict__ ys, const float* __restrict__ embed,
    const float* __restrict__ Wih0, const float* __restrict__ bih0,
    const float* __restrict__ bhh0, u16* __restrict__ gey){
  __shared__ float As[32][68];
  __shared__ float Bs[32][68];
  const int m0 = blockIdx.x*64, n0 = blockIdx.y*64;
  const int tid = threadIdx.x;
  const int ty = tid>>4, tx = tid&15;
  const int ar = tid>>2, akg = (tid&3)*8;
  const int am = m0 + ar;
  const bool arow_on = (am < NROWS);
  int tok = 0;
  if (arow_on){
    int b = am / NOL, l = am - b*NOL;
    tok = (l==0) ? TOK_SOS : ys[b*NL + l - 1];
  }
  const int bj = tid>>2, bkg = (tid&3)*8;
  float acc[4][4] = {{0.0f}};
  for (int k0=0; k0<ND; k0+=32){
    float4 a0 = make_float4(0,0,0,0), a1 = make_float4(0,0,0,0);
    if (arow_on){
      const float4* s = (const float4*)(embed + (size_t)tok*ND + k0 + akg);
      a0 = s[0]; a1 = s[1];
    }
    As[akg+0][ar]=a0.x; As[akg+1][ar]=a0.y; As[akg+2][ar]=a0.z; As[akg+3][ar]=a0.w;
    As[akg+4][ar]=a1.x; As[akg+5][ar]=a1.y; As[akg+6][ar]=a1.z; As[akg+7][ar]=a1.w;
    {
      const float4* s = (const float4*)(Wih0 + (size_t)(n0+bj)*2048 + k0 + bkg);
      float4 b0 = s[0], b1 = s[1];
      Bs[bkg+0][bj]=b0.x; Bs[bkg+1][bj]=b0.y; Bs[bkg+2][bj]=b0.z; Bs[bkg+3][bj]=b0.w;
      Bs[bkg+4][bj]=b1.x; Bs[bkg+5][bj]=b1.y; Bs[bkg+6][bj]=b1.z; Bs[bkg+7][bj]=b1.w;
    }
    __syncthreads();
    #pragma unroll
    for (int kk=0; kk<32; ++kk){
      float4 a = *(const float4*)&As[kk][ty*4];
      float4 b = *(const float4*)&Bs[kk][tx*4];
      float av[4]={a.x,a.y,a.z,a.w}, bv[4]={b.x,b.y,b.z,b.w};
      #pragma unroll
      for (int i=0;i<4;++i)
        #pragma unroll
        for (int j=0;j<4;++j) acc[i][j] += av[i]*bv[j];
    }
    __syncthreads();
  }
  #pragma unroll
  for (int i=0;i<4;++i){
    int row = m0+ty*4+i;
    if (row < NROWS){
      int col = n0 + tx*4;
      u16x4 o = { f2b(acc[i][0]+bih0[col+0]+bhh0[col+0]),
                  f2b(acc[i][1]+bih0[col+1]+bhh0[col+1]),
                  f2b(acc[i][2]+bih0[col+2]+bhh0[col+2]),
                  f2b(acc[i][3]+bih0[col+3]+bhh0[col+3]) };
      *(u16x4*)(gey + (size_t)row*4096 + col) = o;
    }
  }
}

// ---------------- grid barrier: release add + relaxed poll of single-writer go word --------
__device__ __forceinline__ void gbar(u32* bars, u32* go, int slot){
  __syncthreads();
  if (threadIdx.x == 0){
    u32 old = __hip_atomic_fetch_add(&bars[slot], 1u, __ATOMIC_RELEASE, __HIP_MEMORY_SCOPE_AGENT);
    if (old == NBLK-1u){
      coh_stu(go, (u32)(slot+1));
    } else {
      while (coh_ldu(go) < (u32)(slot+1)){
        __builtin_amdgcn_s_sleep(8);
      }
    }
  }
  __syncthreads();
}

// ---------------- persistent sequential kernel: 129 decoder steps ----------------
// grid = 128 blocks x 256 threads (co-resident on 256 CUs)
__global__ __launch_bounds__(256, 1) void seq_kernel(
    const u16* __restrict__ pre,    // [8192][1024] bf16 (cached, read-only)
    const u16* __restrict__ hpadT,  // [16][1024][512] bf16 masked transposed (cached)
    const u16* __restrict__ w0c,    // [4096][1024] bf16 (cached)
    const u16* __restrict__ wh0,    // [4096][1024]
    const u16* __restrict__ w1c,    // [4096][1024]
    const u16* __restrict__ wh1,    // [4096][1024]
    const u16* __restrict__ wdec,   // swizzled tiles (cached)
    const u16* __restrict__ gey,    // [2064][4096] bf16 (cached)
    const float* __restrict__ bias1,// [4096] (cached)
    float* dqf,                     // [16][1024] f32   (coherent)
    float* esc,                     // [16][512] f32    (coherent)
    u16* attc,                      // [16][1024] bf16  (coherent)
    u16* z0bf, u16* z1bf,           // [2][16][1024] bf16 ping-pong (coherent)
    float* c0, float* c1,           // [16][1024] f32 (block-private, cached)
    float* zall,                    // [2064][1024] f32 (read by later kernel)
    u32* bars)
{
  const int wg = blockIdx.x, tid = threadIdx.x;
  const int lane = tid & 63, wv = tid >> 6;
  const int r = lane & 15, q = lane >> 4;
  u32* go = bars + 600;
  __shared__ float sw[512];
  __shared__ float spart[2][128];
  __shared__ float sred[256];
  __shared__ float gex[4][16][16];
  int slot = 0;

  for (int t = 0; t <= NOL; ++t){
    const int cur = t & 1, prv = cur ^ 1;

    // ======== Phase A: dq(t) [wg<64]  ||  gemm1+cell1(t-1) [64<=wg<128] ========
    if (wg < 64){
      if (t < NOL){
        f32x4 acc = {0.f,0.f,0.f,0.f};
        const u16* Ar = z0bf + prv*16384 + r*1024 + q*8;
        const u16* Bw = wdec + (size_t)wg*16384 + lane*8;
        #pragma unroll
        for (int i = 0; i < 8; ++i){
          int kt = wv*8 + i;
          bf16x8 a = coh_ld8h(Ar + kt*32);
          bf16x8 b = *(const bf16x8*)(Bw + (size_t)kt*512);
          acc = __builtin_amdgcn_mfma_f32_16x16x32_bf16(a, b, acc, 0, 0, 0);
        }
        #pragma unroll
        for (int rr = 0; rr < 4; ++rr) gex[wv][q*4+rr][r] = acc[rr];
        __syncthreads();
        {
          int b = tid >> 4, j = tid & 15;
          float s = gex[0][b][j] + gex[1][b][j] + gex[2][b][j] + gex[3][b][j];
          coh_stf(&dqf[b*1024 + wg*16 + j], tanhf(s));
        }
      }
    } else {
      if (t >= 1){
        const int s = t - 1;
        const int dt = wg - 64;
        const int n0 = wv*1024 + dt*16;
        f32x4 acc = {0.f,0.f,0.f,0.f};
        const u16* Ar0 = z0bf + prv*16384 + r*1024 + q*8;
        const u16* Br0 = w1c + (size_t)(n0 + r)*1024 + q*8;
        #pragma unroll 8
        for (int kt = 0; kt < 32; ++kt){
          bf16x8 a = coh_ld8h(Ar0 + kt*32);
          bf16x8 b = *(const bf16x8*)(Br0 + kt*32);
          acc = __builtin_amdgcn_mfma_f32_16x16x32_bf16(a, b, acc, 0, 0, 0);
        }
        const u16* Ar1 = z1bf + cur*16384 + r*1024 + q*8;
        const u16* Br1 = wh1 + (size_t)(n0 + r)*1024 + q*8;
        #pragma unroll 8
        for (int kt = 0; kt < 32; ++kt){
          bf16x8 a = coh_ld8h(Ar1 + kt*32);
          bf16x8 b = *(const bf16x8*)(Br1 + kt*32);
          acc = __builtin_amdgcn_mfma_f32_16x16x32_bf16(a, b, acc, 0, 0, 0);
        }
        #pragma unroll
        for (int rr = 0; rr < 4; ++rr) gex[wv][q*4+rr][r] = acc[rr];
        __syncthreads();
        {
          int b = tid >> 4, dj = tid & 15, d = dt*16 + dj, idx = b*1024 + d;
          float gi = gex[0][b][dj] + bias1[d];
          float gf = gex[1][b][dj] + bias1[1024 + d];
          float gg = gex[2][b][dj] + bias1[2048 + d];
          float go_ = gex[3][b][dj] + bias1[3072 + d];
          float cn = sigf(gf)*c1[idx] + sigf(gi)*tanhf(gg);
          float zn = sigf(go_)*tanhf(cn);
          c1[idx] = cn;
          zall[((size_t)b*NOL + s)*1024 + d] = zn;
          float znn = __shfl_down(zn, 1);
          if ((dj & 1) == 0){
            u32 pk = (u32)f2b(zn) | ((u32)f2b(znn) << 16);
            coh_stu((u32*)(z1bf + prv*16384 + idx), pk);
          }
        }
      }
    }
    gbar(bars, go, slot++);
    if (t == NOL) break;

    // ======== Phase B: escore(t) = 2 * pre . dq  (128 WGs, 16 rows/wave) ========
    {
      const int rbase = (wg*4 + wv)*16;
      const int b = rbase >> 9;
      float qv[16];
      const float* dqb = dqf + b*1024 + lane*16;
      #pragma unroll
      for (int j = 0; j < 16; ++j) qv[j] = coh_ldf(dqb + j);
      #pragma unroll 4
      for (int rr = 0; rr < 16; ++rr){
        const u16* pr = pre + (size_t)(rbase+rr)*1024 + lane*16;
        u16x8 p0 = *(const u16x8*)(pr);
        u16x8 p1 = *(const u16x8*)(pr+8);
        float acc = 0.f;
        #pragma unroll
        for (int j = 0; j < 8; ++j){
          acc += b2f(p0[j])*qv[j];
          acc += b2f(p1[j])*qv[8+j];
        }
        #pragma unroll
        for (int off = 32; off > 0; off >>= 1) acc += __shfl_xor(acc, off, 64);
        if (lane == 0) coh_stf(&esc[rbase+rr], 2.0f*acc);
      }
    }
    gbar(bars, go, slot++);

    // ======== Phase C: softmax + att_c  (128 WGs: b = wg>>3, 128-col e-slice) ========
    {
      const int b = wg >> 3, ec = wg & 7;
      float e0 = coh_ldf(&esc[b*512 + tid]);
      float e1 = coh_ldf(&esc[b*512 + tid + 256]);
      sred[tid] = fmaxf(e0, e1);
      __syncthreads();
      #pragma unroll
      for (int s2 = 128; s2 > 0; s2 >>= 1){
        if (tid < s2) sred[tid] = fmaxf(sred[tid], sred[tid+s2]);
        __syncthreads();
      }
      float mx = sred[0];
      __syncthreads();
      float p0 = expf(e0 - mx), p1 = expf(e1 - mx);
      sred[tid] = p0 + p1;
      __syncthreads();
      #pragma unroll
      for (int s2 = 128; s2 > 0; s2 >>= 1){
        if (tid < s2) sred[tid] += sred[tid+s2];
        __syncthreads();
      }
      float inv = 1.0f/sred[0];
      sw[tid] = p0*inv; sw[tid+256] = p1*inv;
      __syncthreads();
      const int el = tid & 127, th = tid >> 7;
      const int e = ec*128 + el;
      const u16* hp = hpadT + ((size_t)b*1024 + e)*512 + th*256;
      float acc = 0.f;
      #pragma unroll 8
      for (int tt = 0; tt < 256; tt += 8){
        u16x8 v = *(const u16x8*)(hp + tt);
        #pragma unroll
        for (int j = 0; j < 8; ++j) acc += sw[th*256 + tt + j]*b2f(v[j]);
      }
      spart[th][el] = acc;
      __syncthreads();
      if (tid < 128){
        float s2 = spart[0][tid] + spart[1][tid];
        float s2n = __shfl_down(s2, 1);
        if ((tid & 1) == 0){
          u32 pk = (u32)f2b(s2) | ((u32)f2b(s2n) << 16);
          coh_stu((u32*)(attc + b*1024 + ec*128 + tid), pk);
        }
      }
    }
    gbar(bars, go, slot++);

    // ======== Phase D: gemm0 + cell0(t) [wg<64] ========
    if (wg < 64){
      const int n0 = wv*1024 + wg*16;
      f32x4 acc = {0.f,0.f,0.f,0.f};
      const u16* Ar0 = attc + r*1024 + q*8;
      const u16* Br0 = w0c + (size_t)(n0 + r)*1024 + q*8;
      #pragma unroll 8
      for (int kt = 0; kt < 32; ++kt){
        bf16x8 a = coh_ld8h(Ar0 + kt*32);
        bf16x8 b = *(const bf16x8*)(Br0 + kt*32);
        acc = __builtin_amdgcn_mfma_f32_16x16x32_bf16(a, b, acc, 0, 0, 0);
      }
      const u16* Ar1 = z0bf + prv*16384 + r*1024 + q*8;
      const u16* Br1 = wh0 + (size_t)(n0 + r)*1024 + q*8;
      #pragma unroll 8
      for (int kt = 0; kt < 32; ++kt){
        bf16x8 a = coh_ld8h(Ar1 + kt*32);
        bf16x8 b = *(const bf16x8*)(Br1 + kt*32);
        acc = __builtin_amdgcn_mfma_f32_16x16x32_bf16(a, b, acc, 0, 0, 0);
      }
      #pragma unroll
      for (int rr = 0; rr < 4; ++rr) gex[wv][q*4+rr][r] = acc[rr];
      __syncthreads();
      {
        int b = tid >> 4, dj = tid & 15, d = wg*16 + dj, idx = b*1024 + d;
        const u16* gr = gey + ((size_t)b*NOL + t)*4096 + d;
        float gi = gex[0][b][dj] + b2f(gr[0]);
        float gf = gex[1][b][dj] + b2f(gr[1024]);
        float gg = gex[2][b][dj] + b2f(gr[2048]);
        float go_ = gex[3][b][dj] + b2f(gr[3072]);
        float cn = sigf(gf)*c0[idx] + sigf(gi)*tanhf(gg);
        float zn = sigf(go_)*tanhf(cn);
        c0[idx] = cn;
        float znn = __shfl_down(zn, 1);
        if ((dj & 1) == 0){
          u32 pk = (u32)f2b(zn) | ((u32)f2b(znn) << 16);
          coh_stu((u32*)(z0bf + cur*16384 + idx), pk);
        }
      }
    }
    gbar(bars, go, slot++);
  }
}

// ---------------- logits = z_all @ Wout + bout -> bf16 [2064][10000] ----------------
__global__ __launch_bounds__(256) void logits_kernel(
    const float* __restrict__ zall, const float* __restrict__ Wout,
    const float* __restrict__ bout, u16* __restrict__ logits){
  __shared__ float As[32][68];
  __shared__ float Bs[32][68];
  const int m0 = blockIdx.x*64, n0 = blockIdx.y*64;
  const int tid = threadIdx.x;
  const int ty = tid>>4, tx = tid&15;
  const int ar = tid>>2, akg = (tid&3)*8;
  const int am = m0 + ar;
  const bool arow_on = (am < NROWS);
  const int bk = tid>>3, bng = (tid&7)*8;
  const bool nfull = (n0 + 64 <= NO);
  float acc[4][4] = {{0.0f}};
  for (int k0=0; k0<ND; k0+=32){
    float4 a0 = make_float4(0,0,0,0), a1 = make_float4(0,0,0,0);
    if (arow_on){
      const float4* s = (const float4*)(zall + (size_t)am*ND + k0 + akg);
      a0 = s[0]; a1 = s[1];
    }
    As[akg+0][ar]=a0.x; As[akg+1][ar]=a0.y; As[akg+2][ar]=a0.z; As[akg+3][ar]=a0.w;
    As[akg+4][ar]=a1.x; As[akg+5][ar]=a1.y; As[akg+6][ar]=a1.z; As[akg+7][ar]=a1.w;
    if (nfull){
      const float4* s = (const float4*)(Wout + (size_t)(k0+bk)*NO + n0 + bng);
      *(float4*)&Bs[bk][bng]   = s[0];
      *(float4*)&Bs[bk][bng+4] = s[1];
    } else {
      #pragma unroll
      for (int i=0;i<8;++i){
        int n = n0 + bng + i;
        Bs[bk][bng+i] = (n < NO) ? Wout[(size_t)(k0+bk)*NO + n] : 0.0f;
      }
    }
    __syncthreads();
    #pragma unroll
    for (int kk=0; kk<32; ++kk){
      float4 a = *(const float4*)&As[kk][ty*4];
      float4 b = *(const float4*)&Bs[kk][tx*4];
      float av[4]={a.x,a.y,a.z,a.w}, bv[4]={b.x,b.y,b.z,b.w};
      #pragma unroll
      for (int i=0;i<4;++i)
        #pragma unroll
        for (int j=0;j<4;++j) acc[i][j] += av[i]*bv[j];
    }
    __syncthreads();
  }
  #pragma unroll
  for (int i=0;i<4;++i){
    int row = m0+ty*4+i;
    if (row < NROWS){
      #pragma unroll
      for (int j=0;j<4;++j){
        int col = n0 + tx*4 + j;
        if (col < NO) logits[(size_t)row*NO + col] = f2b(acc[i][j] + bout[col]);
      }
    }
  }
}

// ---------------- per-row log_softmax + NLL + argmax (bf16 logits) ----------------
__global__ __launch_bounds__(256) void loss_kernel(
    const u16* __restrict__ logits, const int* __restrict__ ys, float* __restrict__ accum){
  int row = blockIdx.x;
  int tid = threadIdx.x;
  const u16* lr = logits + (size_t)row * NO;
  __shared__ float sv[256];
  __shared__ int   si[256];
  float mx = -INFINITY; int mi = 0;
  for (int n = tid; n < NO; n += 256){
    float v = b2f(lr[n]);
    if (v > mx){ mx = v; mi = n; }
  }
  sv[tid] = mx; si[tid] = mi;
  __syncthreads();
  for (int s=128; s>0; s>>=1){
    if (tid < s){
      if (sv[tid+s] > sv[tid] || (sv[tid+s]==sv[tid] && si[tid+s] < si[tid])){
        sv[tid] = sv[tid+s]; si[tid] = si[tid+s];
      }
    }
    __syncthreads();
  }
  float gmx = sv[0]; int gmi = si[0];
  __syncthreads();
  float ps = 0.0f;
  for (int n = tid; n < NO; n += 256) ps += expf(b2f(lr[n])-gmx);
  sv[tid] = ps;
  __syncthreads();
  for (int s=128; s>0; s>>=1){ if (tid<s) sv[tid] += sv[tid+s]; __syncthreads(); }
  if (tid==0){
    int b = row / NOL, l = row - b*NOL;
    int label = (l < NL) ? ys[b*NL + l] : TOK_EOS;
    float lse = gmx + logf(sv[0]);
    float nll = lse - b2f(lr[label]);
    atomicAdd(&accum[0], nll);
    atomicAdd(&accum[1], (gmi==label) ? 1.0f : 0.0f);
  }
}

__global__ void finalize_kernel(const float* __restrict__ accum, float* __restrict__ out){
  out[0] = accum[0] / (float)NROWS * (float)(NOL-1);
  out[1] = accum[1] / (float)NROWS;
}

extern "C" void kernel_launch(void* const* d_in, const int* in_sizes, int n_in,
                              void* d_out, int out_size, void* d_ws, size_t ws_size,
                              hipStream_t stream){
  const float* hpad  = (const float*)d_in[0];
  const int*   hlen  = (const int*)  d_in[1];
  const int*   ys    = (const int*)  d_in[2];
  const float* embed = (const float*)d_in[3];
  const float* Wenc  = (const float*)d_in[4];
  const float* Wdec  = (const float*)d_in[5];
  const float* Wih0  = (const float*)d_in[6];
  const float* Whh0  = (const float*)d_in[7];
  const float* bih0  = (const float*)d_in[8];
  const float* bhh0  = (const float*)d_in[9];
  const float* Wih1  = (const float*)d_in[10];
  const float* Whh1  = (const float*)d_in[11];
  const float* bih1  = (const float*)d_in[12];
  const float* bhh1  = (const float*)d_in[13];
  const float* Wout  = (const float*)d_in[14];
  const float* bout  = (const float*)d_in[15];
  float* out = (float*)d_out;

  char* ws = (char*)d_ws;
  size_t cur = 0;
  auto alloc = [&](size_t bytes) -> char* {
    char* p = ws + cur;
    cur += (bytes + 255) & ~(size_t)255;
    return p;
  };
  u16*   pre_bf   = (u16*)  alloc(16777216);   // [8192][1024]
  u16*   hpadT    = (u16*)  alloc(16777216);   // [16][1024][512]
  u16*   w0c      = (u16*)  alloc(8388608);    // Wih0[:,1024:]
  u16*   wh0      = (u16*)  alloc(8388608);
  u16*   w1c      = (u16*)  alloc(8388608);
  u16*   wh1      = (u16*)  alloc(8388608);
  u16*   wdec_sw  = (u16*)  alloc(2097152);
  u16*   gey      = (u16*)  alloc(16908288);   // [2064][4096]
  float* zall     = (float*)alloc(8454144);    // [2064][1024]
  u16*   logits   = (u16*)  alloc(41280000);   // [2064][10000]
  float* dqf      = (float*)alloc(65536);
  float* esc      = (float*)alloc(32768);
  u16*   attc     = (u16*)  alloc(32768);
  float* bias1    = (float*)alloc(16384);
  // ---- zeroed region (contiguous) ----
  u32*   bars     = (u32*)  alloc(2560);       // slots 0..516, go at [600]
  u16*   z0bf     = (u16*)  alloc(65536);      // [2][16][1024]
  u16*   z1bf     = (u16*)  alloc(65536);
  float* c0       = (float*)alloc(65536);
  float* c1       = (float*)alloc(65536);
  float* accum    = (float*)alloc(128);
  // zero bytes = 2560 + 4*65536 + 128 = 264832 -> 16552 uint4
  zero4_kernel<<<65, 256, 0, stream>>>((uint4*)bars, 16552);

  cvt_nk_kernel<<<4096, 256, 0, stream>>>(Wih0, 2048, 1024, w0c);
  cvt_nk_kernel<<<4096, 256, 0, stream>>>(Whh0, 1024, 0, wh0);
  cvt_nk_kernel<<<4096, 256, 0, stream>>>(Wih1, 1024, 0, w1c);
  cvt_nk_kernel<<<4096, 256, 0, stream>>>(Whh1, 1024, 0, wh1);
  wdec_swz_kernel<<<4096, 256, 0, stream>>>(Wdec, wdec_sw);
  hpadT_kernel<<<dim3(32,16,16), 256, 0, stream>>>(hpad, hlen, hpadT);
  bias_add_kernel<<<16, 256, 0, stream>>>(bih1, bhh1, bias1);
  preenc_kernel<<<dim3(128,16), 256, 0, stream>>>(hpad, hlen, Wenc, pre_bf);
  gey_kernel<<<dim3(33,64), 256, 0, stream>>>(ys, embed, Wih0, bih0, bhh0, gey);

  seq_kernel<<<NBLK, 256, 0, stream>>>(pre_bf, hpadT, w0c, wh0, w1c, wh1,
                                       wdec_sw, gey, bias1, dqf, esc, attc,
                                       z0bf, z1bf, c0, c1, zall, bars);

  logits_kernel<<<dim3(33,157), 256, 0, stream>>>(zall, Wout, bout, logits);
  loss_kernel<<<NROWS, 256, 0, stream>>>(logits, ys, accum);
  finalize_kernel<<<1, 1, 0, stream>>>(accum, out);
}

// Round 4
// 7727.010 us; speedup vs baseline: 3.9173x; 1.8920x over previous
//
#include <hip/hip_runtime.h>
#include <math.h>

#define NB 16
#define NT 512
#define NE 1024
#define ND 1024
#define NA 1024
#define NO 10000
#define NL 128
#define NOL 129
#define NROWS (NB*NOL)   /* 2064 */
#define TOK_SOS 9999
#define TOK_EOS 9999
#define NBLK 256

typedef unsigned short u16;
typedef unsigned int u32;
typedef __bf16 bf16x8 __attribute__((ext_vector_type(8)));
typedef float f32x4 __attribute__((ext_vector_type(4)));
typedef unsigned short u16x8 __attribute__((ext_vector_type(8)));
typedef unsigned short u16x4 __attribute__((ext_vector_type(4)));

__device__ __forceinline__ float sigf(float x){ return 1.0f/(1.0f+expf(-x)); }
__device__ __forceinline__ float b2f(u16 s){
  union { u32 i; float f; } u; u.i = ((u32)s) << 16; return u.f;
}
__device__ __forceinline__ u16 f2b(float f){
  union { float f; u32 i; } u; u.f = f;
  u32 r = u.i + 0x7FFFu + ((u.i >> 16) & 1u);
  return (u16)(r >> 16);
}
__device__ __forceinline__ bf16x8 cvt8(float4 a, float4 b){
  union { u16 u[8]; bf16x8 v; } c;
  c.u[0]=f2b(a.x); c.u[1]=f2b(a.y); c.u[2]=f2b(a.z); c.u[3]=f2b(a.w);
  c.u[4]=f2b(b.x); c.u[5]=f2b(b.y); c.u[6]=f2b(b.z); c.u[7]=f2b(b.w);
  return c.v;
}
__device__ __forceinline__ bf16x8 zero8(){
  union { u16 u[8]; bf16x8 v; } c;
  #pragma unroll
  for (int i=0;i<8;++i) c.u[i]=0;
  return c.v;
}

// ---- coherent (cache-bypassing, relaxed) helpers ----
__device__ __forceinline__ float coh_ldf(const float* p){
  return __hip_atomic_load((float*)p, __ATOMIC_RELAXED, __HIP_MEMORY_SCOPE_AGENT);
}
__device__ __forceinline__ void coh_stf(float* p, float v){
  __hip_atomic_store(p, v, __ATOMIC_RELAXED, __HIP_MEMORY_SCOPE_AGENT);
}
__device__ __forceinline__ u32 coh_ldu(const u32* p){
  return __hip_atomic_load((u32*)p, __ATOMIC_RELAXED, __HIP_MEMORY_SCOPE_AGENT);
}
__device__ __forceinline__ void coh_stu(u32* p, u32 v){
  __hip_atomic_store(p, v, __ATOMIC_RELAXED, __HIP_MEMORY_SCOPE_AGENT);
}
__device__ __forceinline__ bf16x8 coh_ld8h(const u16* p){
  const u32* q = (const u32*)p;
  union { u32 u[4]; bf16x8 b; } c;
  c.u[0] = coh_ldu(q+0); c.u[1] = coh_ldu(q+1);
  c.u[2] = coh_ldu(q+2); c.u[3] = coh_ldu(q+3);
  return c.b;
}
__device__ __forceinline__ float dot8(bf16x8 a, bf16x8 b){
  float s = 0.f;
  #pragma unroll
  for (int j=0;j<8;++j) s += (float)a[j]*(float)b[j];
  return s;
}

// ---------------- zero ----------------
__global__ void zero4_kernel(uint4* __restrict__ p, int n){
  int i = blockIdx.x*256 + threadIdx.x;
  if (i < n) p[i] = make_uint4(0,0,0,0);
}

// ---------------- f32 [4096][ld] (col slice) -> bf16 [4096][1024] ----------------
__global__ __launch_bounds__(256) void cvt_nk_kernel(
    const float* __restrict__ src, int ld, int off, u16* __restrict__ dst){
  int i = (blockIdx.x*256 + threadIdx.x)*4;
  int row = i >> 10, col = i & 1023;
  float4 v = *(const float4*)(src + (size_t)row*ld + off + col);
  u16x4 o = { f2b(v.x), f2b(v.y), f2b(v.z), f2b(v.w) };
  *(u16x4*)(dst + i) = o;
}

// ---------------- transpose-convert: src f32 [R][C] -> dst bf16 [C'][R] ----------------
__global__ __launch_bounds__(256) void tcvt_kernel(
    const float* __restrict__ src, int R, int C, u16* __restrict__ dst){
  __shared__ float tile[32][33];
  const int c0 = blockIdx.x*32, r0 = blockIdx.y*32;
  const int tx = threadIdx.x & 31, ty = threadIdx.x >> 5;
  #pragma unroll
  for (int k = 0; k < 4; ++k){
    int rr = ty + k*8;
    int c = c0 + tx;
    float v = (c < C) ? src[(size_t)(r0+rr)*C + c] : 0.0f;
    tile[rr][tx] = v;
  }
  __syncthreads();
  #pragma unroll
  for (int k = 0; k < 4; ++k){
    int cc = ty + k*8;
    dst[(size_t)(c0+cc)*R + r0 + tx] = f2b(tile[tx][cc]);
  }
}

// ---------------- hpad [16][512][1024] f32 -> masked bf16 transposed [16][1024][512] -------
__global__ __launch_bounds__(256) void hpadT_kernel(
    const float* __restrict__ hpad, const int* __restrict__ hlen, u16* __restrict__ dst){
  __shared__ float tile[32][33];
  const int e0 = blockIdx.x*32, t0 = blockIdx.y*32, b = blockIdx.z;
  const int tx = threadIdx.x & 31, ty = threadIdx.x >> 5;
  const int len = hlen[b];
  #pragma unroll
  for (int k = 0; k < 4; ++k){
    int r = ty + k*8;
    tile[r][tx] = hpad[((size_t)b*512 + t0 + r)*1024 + e0 + tx];
  }
  __syncthreads();
  #pragma unroll
  for (int k = 0; k < 4; ++k){
    int el = ty + k*8;
    float m = (t0 + tx < len) ? 1.0f : 0.0f;
    dst[((size_t)b*1024 + e0 + el)*512 + t0 + tx] = f2b(tile[tx][el]*m);
  }
}

// ---------------- bias1 = bih1 + bhh1 ----------------
__global__ void bias_add_kernel(const float* __restrict__ a, const float* __restrict__ b,
                                float* __restrict__ o){
  int i = blockIdx.x*256 + threadIdx.x;
  if (i < 4096) o[i] = a[i] + b[i];
}

// ---------------- pre_enc = tanh(mask(hpad) @ Wenc) via MFMA -> bf16 [8192][1024] ----------
__global__ __launch_bounds__(256) void preenc_mfma(
    const float* __restrict__ hpad, const int* __restrict__ hlen,
    const u16* __restrict__ wencT, u16* __restrict__ pre){
  const int m0 = blockIdx.x*64, n0 = blockIdx.y*64;
  const int tid = threadIdx.x, lane = tid & 63, wv = tid >> 6;
  const int r = lane & 15, q = lane >> 4;
  const int ar = m0 + wv*16 + r;
  const bool on = (ar & 511) < hlen[ar >> 9];
  const float* ap = hpad + (size_t)ar*1024 + q*8;
  f32x4 acc[4] = {{0,0,0,0},{0,0,0,0},{0,0,0,0},{0,0,0,0}};
  for (int kt = 0; kt < 32; ++kt){
    bf16x8 a;
    if (on){
      float4 v0 = *(const float4*)(ap + kt*32);
      float4 v1 = *(const float4*)(ap + kt*32 + 4);
      a = cvt8(v0, v1);
    } else a = zero8();
    #pragma unroll
    for (int s = 0; s < 4; ++s){
      const u16* bp = wencT + (size_t)(n0 + s*16 + r)*1024 + kt*32 + q*8;
      acc[s] = __builtin_amdgcn_mfma_f32_16x16x32_bf16(a, *(const bf16x8*)bp, acc[s], 0,0,0);
    }
  }
  #pragma unroll
  for (int s = 0; s < 4; ++s)
    #pragma unroll
    for (int rr = 0; rr < 4; ++rr){
      int row = m0 + wv*16 + q*4 + rr, col = n0 + s*16 + r;
      pre[(size_t)row*1024 + col] = f2b(tanhf(acc[s][rr]));
    }
}

// ---------------- gey = embed[ys_in] @ Wih0[:,0:1024]^T + bih0 + bhh0 via MFMA -> bf16 -----
__global__ __launch_bounds__(256) void gey_mfma(
    const int* __restrict__ ys, const float* __restrict__ embed,
    const float* __restrict__ Wih0, const float* __restrict__ bih0,
    const float* __restrict__ bhh0, u16* __restrict__ gey){
  const int m0 = blockIdx.x*64, n0 = blockIdx.y*64;
  const int tid = threadIdx.x, lane = tid & 63, wv = tid >> 6;
  const int r = lane & 15, q = lane >> 4;
  const int ar = m0 + wv*16 + r;
  int tok = 0;
  if (ar < NROWS){
    int bb = ar / NOL, l = ar - bb*NOL;
    tok = (l==0) ? TOK_SOS : ys[bb*NL + l - 1];
  }
  const float* ap = embed + (size_t)tok*1024 + q*8;
  f32x4 acc[4] = {{0,0,0,0},{0,0,0,0},{0,0,0,0},{0,0,0,0}};
  for (int kt = 0; kt < 32; ++kt){
    float4 v0 = *(const float4*)(ap + kt*32);
    float4 v1 = *(const float4*)(ap + kt*32 + 4);
    bf16x8 a = cvt8(v0, v1);
    #pragma unroll
    for (int s = 0; s < 4; ++s){
      const float* bp = Wih0 + (size_t)(n0 + s*16 + r)*2048 + kt*32 + q*8;
      float4 w0 = *(const float4*)(bp);
      float4 w1 = *(const float4*)(bp + 4);
      acc[s] = __builtin_amdgcn_mfma_f32_16x16x32_bf16(a, cvt8(w0,w1), acc[s], 0,0,0);
    }
  }
  #pragma unroll
  for (int s = 0; s < 4; ++s)
    #pragma unroll
    for (int rr = 0; rr < 4; ++rr){
      int row = m0 + wv*16 + q*4 + rr, col = n0 + s*16 + r;
      if (row < NROWS)
        gey[(size_t)row*4096 + col] = f2b(acc[s][rr] + bih0[col] + bhh0[col]);
    }
}

// ---------------- logits = zallb @ woutT^T + bout via MFMA -> bf16 [2064][10000] -----------
__global__ __launch_bounds__(256) void logits_mfma(
    const u16* __restrict__ zallb, const u16* __restrict__ woutT,
    const float* __restrict__ bout, u16* __restrict__ logits){
  const int m0 = blockIdx.x*64, n0 = blockIdx.y*64;
  const int tid = threadIdx.x, lane = tid & 63, wv = tid >> 6;
  const int r = lane & 15, q = lane >> 4;
  const int ar = m0 + wv*16 + r;
  const u16* ap = zallb + (size_t)ar*1024 + q*8;
  f32x4 acc[4] = {{0,0,0,0},{0,0,0,0},{0,0,0,0},{0,0,0,0}};
  for (int kt = 0; kt < 32; ++kt){
    bf16x8 a = *(const bf16x8*)(ap + kt*32);
    #pragma unroll
    for (int s = 0; s < 4; ++s){
      const u16* bp = woutT + (size_t)(n0 + s*16 + r)*1024 + kt*32 + q*8;
      acc[s] = __builtin_amdgcn_mfma_f32_16x16x32_bf16(a, *(const bf16x8*)bp, acc[s], 0,0,0);
    }
  }
  #pragma unroll
  for (int s = 0; s < 4; ++s)
    #pragma unroll
    for (int rr = 0; rr < 4; ++rr){
      int row = m0 + wv*16 + q*4 + rr, col = n0 + s*16 + r;
      if (row < NROWS && col < NO)
        logits[(size_t)row*NO + col] = f2b(acc[s][rr] + bout[col]);
    }
}

// ---------------- grid barrier ----------------
__device__ __forceinline__ void gbar(u32* bars, u32* go, int slot){
  __syncthreads();
  if (threadIdx.x == 0){
    u32 old = __hip_atomic_fetch_add(&bars[slot], 1u, __ATOMIC_RELEASE, __HIP_MEMORY_SCOPE_AGENT);
    if (old == NBLK-1u){
      coh_stu(go, (u32)(slot+1));
    } else {
      while (coh_ldu(go) < (u32)(slot+1)){
        __builtin_amdgcn_s_sleep(8);
      }
    }
  }
  __syncthreads();
}

// one 16x16 output tile, K=512 slice per wave, weights from LDS
__device__ __forceinline__ f32x4 tile_gemm(const u16* lw, const u16* ab){
  f32x4 acc = {0.f,0.f,0.f,0.f};
  #pragma unroll
  for (int kt = 0; kt < 16; ++kt){
    bf16x8 a = coh_ld8h(ab + kt*32);
    bf16x8 b = *(const bf16x8*)(lw + kt*512);
    acc = __builtin_amdgcn_mfma_f32_16x16x32_bf16(a, b, acc, 0, 0, 0);
  }
  return acc;
}

// ---------------- persistent sequential kernel: 256 WGs, weights LDS-resident ----------------
__global__ __launch_bounds__(256, 1) void seq_kernel(
    const u16* __restrict__ pre,    // [8192][1024] bf16
    const u16* __restrict__ hpadT,  // [16][1024][512] bf16 masked
    const u16* __restrict__ w0c,    // [4096][1024] Wih0[:,1024:] bf16
    const u16* __restrict__ wh0,    // [4096][1024]
    const u16* __restrict__ w1c,    // [4096][1024]
    const u16* __restrict__ wh1,    // [4096][1024]
    const u16* __restrict__ wdecT,  // [1024 n][1024 k] bf16
    const u16* __restrict__ gey,    // [2064][4096] bf16
    const float* __restrict__ bias1,// [4096]
    const int* __restrict__ hlen,
    float* dqf,                     // [16][1024] f32   (coherent)
    float* esc,                     // [8192] f32       (coherent)
    u16* attc,                      // [16][1024] bf16  (coherent)
    u16* z0bf, u16* z1bf,           // [2][16][1024] bf16 ping-pong (coherent)
    u16* zallb,                     // [2112][1024] bf16
    u32* bars)
{
  const int wg = blockIdx.x, tid = threadIdx.x;
  const int lane = tid & 63, wv = tid >> 6;
  const int r = lane & 15, q = lane >> 4;
  u32* go = bars + 600;

  extern __shared__ __align__(16) u16 dynlds[];
  u16* lw1 = dynlds;            // 16 rows x 2048 K swizzled [kb][16][8] = 64 KB
  u16* lw0 = dynlds + 32768;    // 64 KB
  __shared__ float sred[256];
  __shared__ float sw[512];
  __shared__ float spart[4][64];
  __shared__ float gex[4][16][16];
  __shared__ float sdq[16*16*4];

  const int dg16 = (wg & 63)*16, sub4 = (wg >> 6)*4;

  // ---- stage weights into LDS (once) ----
  {
    const int kb = tid;              // 0..255
    const int k0 = kb*8;
    #pragma unroll
    for (int c = 0; c < 16; ++c){
      int gi = c >> 2;
      int d  = dg16 + sub4 + (c & 3);
      size_t gr = (size_t)(gi*1024 + d)*1024;
      const u16* s1 = (k0 < 1024) ? (w1c + gr + k0) : (wh1 + gr + k0 - 1024);
      const u16* s0 = (k0 < 1024) ? (w0c + gr + k0) : (wh0 + gr + k0 - 1024);
      *(u16x8*)(lw1 + ((kb*16 + c) << 3)) = *(const u16x8*)s1;
      *(u16x8*)(lw0 + ((kb*16 + c) << 3)) = *(const u16x8*)s0;
    }
  }
  __syncthreads();

  float c0r = 0.f, c1r = 0.f;    // cell states, owned by tid<64 (b=tid>>2, dd=tid&3)
  int slot = 0;
  const int lwoff = ((wv*64 + q)*16 + r) << 3;

  for (int t = 0; t <= NOL; ++t){
    const int cur = t & 1, prv = cur ^ 1;

    // ======== Phase A: gemm1+cell1(t-1) + dq(t), all WGs ========
    if (t >= 1){
      const int s = t - 1;
      const u16* z0p = z0bf + prv*16384;
      const u16* z1p = z1bf + cur*16384;
      const u16* ab = ((wv < 2) ? z0p : z1p) + r*1024 + (wv & 1)*512 + q*8;
      f32x4 acc = tile_gemm(lw1 + lwoff, ab);
      #pragma unroll
      for (int rr = 0; rr < 4; ++rr) gex[wv][q*4+rr][r] = acc[rr];
      __syncthreads();
      if (tid < 64){
        int b = tid >> 2, dd = tid & 3, d = dg16 + sub4 + dd;
        float g[4];
        #pragma unroll
        for (int gi = 0; gi < 4; ++gi)
          g[gi] = gex[0][b][gi*4+dd] + gex[1][b][gi*4+dd]
                + gex[2][b][gi*4+dd] + gex[3][b][gi*4+dd] + bias1[gi*1024 + d];
        float cn = sigf(g[1])*c1r + sigf(g[0])*tanhf(g[2]);
        float zn = sigf(g[3])*tanhf(cn);
        c1r = cn;
        float zn2 = __shfl_down(zn, 1);
        if ((tid & 1) == 0){
          u32 pk = (u32)f2b(zn) | ((u32)f2b(zn2) << 16);
          *(u32*)(zallb + ((size_t)b*NOL + s)*1024 + d) = pk;
          coh_stu((u32*)(z1bf + prv*16384 + b*1024 + d), pk);
        }
      }
      __syncthreads();
    }
    if (t < NOL){
      // dq: this WG computes n = wg*4 .. wg*4+3 for all 16 batches
      const u16* z0p = z0bf + prv*16384;
      const int b = tid & 15, ks = tid >> 4;
      float a4[4] = {0.f,0.f,0.f,0.f};
      #pragma unroll
      for (int i = 0; i < 8; ++i){
        bf16x8 za = coh_ld8h(z0p + b*1024 + ks*64 + i*8);
        #pragma unroll
        for (int nn = 0; nn < 4; ++nn){
          bf16x8 wb = *(const bf16x8*)(wdecT + (size_t)(wg*4+nn)*1024 + ks*64 + i*8);
          a4[nn] += dot8(za, wb);
        }
      }
      #pragma unroll
      for (int nn = 0; nn < 4; ++nn) sdq[(ks*16 + b)*4 + nn] = a4[nn];
      __syncthreads();
      if (tid < 64){
        int b2 = tid >> 2, nn = tid & 3;
        float s2 = 0.f;
        #pragma unroll
        for (int ks2 = 0; ks2 < 16; ++ks2) s2 += sdq[(ks2*16 + b2)*4 + nn];
        coh_stf(dqf + b2*1024 + wg*4 + nn, tanhf(s2));
      }
    }
    gbar(bars, go, slot++);
    if (t == NOL) break;

    // ======== Phase B: escore = 2 * pre . dq  (32 rows per WG) ========
    {
      const int rbase = wg*32 + wv*8;
      const int b = (wg*32) >> 9;
      float qv[16];
      const float* dqb = dqf + b*1024 + lane*16;
      #pragma unroll
      for (int j = 0; j < 16; ++j) qv[j] = coh_ldf(dqb + j);
      #pragma unroll
      for (int rr = 0; rr < 8; ++rr){
        const u16* pr = pre + (size_t)(rbase+rr)*1024 + lane*16;
        u16x8 p0 = *(const u16x8*)(pr);
        u16x8 p1 = *(const u16x8*)(pr+8);
        float acc = 0.f;
        #pragma unroll
        for (int j = 0; j < 8; ++j){
          acc += b2f(p0[j])*qv[j];
          acc += b2f(p1[j])*qv[8+j];
        }
        #pragma unroll
        for (int off = 32; off > 0; off >>= 1) acc += __shfl_xor(acc, off, 64);
        if (lane == 0) coh_stf(&esc[rbase+rr], 2.0f*acc);
      }
    }
    gbar(bars, go, slot++);

    // ======== Phase C: softmax + att_c (b = wg>>4, 64-col e-slice) ========
    {
      const int b = wg >> 4, ec = wg & 15;
      const int len = hlen[b];
      float e0 = (tid < len)     ? coh_ldf(&esc[b*512 + tid])       : -INFINITY;
      float e1 = (tid+256 < len) ? coh_ldf(&esc[b*512 + tid + 256]) : -INFINITY;
      sred[tid] = fmaxf(e0, e1);
      __syncthreads();
      #pragma unroll
      for (int s2 = 128; s2 > 0; s2 >>= 1){
        if (tid < s2) sred[tid] = fmaxf(sred[tid], sred[tid+s2]);
        __syncthreads();
      }
      float mx = sred[0];
      __syncthreads();
      float p0 = (tid < len)     ? expf(e0 - mx) : 0.0f;
      float p1 = (tid+256 < len) ? expf(e1 - mx) : 0.0f;
      sred[tid] = p0 + p1;
      __syncthreads();
      #pragma unroll
      for (int s2 = 128; s2 > 0; s2 >>= 1){
        if (tid < s2) sred[tid] += sred[tid+s2];
        __syncthreads();
      }
      float inv = 1.0f/sred[0];
      sw[tid] = p0*inv; sw[tid+256] = p1*inv;
      __syncthreads();
      const int el = tid & 63, th = tid >> 6;
      const u16* hp = hpadT + ((size_t)b*1024 + ec*64 + el)*512 + th*128;
      float acc = 0.f;
      #pragma unroll
      for (int i = 0; i < 16; ++i){
        u16x8 v = *(const u16x8*)(hp + i*8);
        #pragma unroll
        for (int j = 0; j < 8; ++j) acc += sw[th*128 + i*8 + j]*b2f(v[j]);
      }
      spart[th][el] = acc;
      __syncthreads();
      if (tid < 64){
        float s2 = spart[0][tid]+spart[1][tid]+spart[2][tid]+spart[3][tid];
        float s2n = __shfl_down(s2, 1);
        if ((tid & 1) == 0){
          u32 pk = (u32)f2b(s2) | ((u32)f2b(s2n) << 16);
          coh_stu((u32*)(attc + b*1024 + ec*64 + tid), pk);
        }
      }
    }
    gbar(bars, go, slot++);

    // ======== Phase D: gemm0 + cell0(t), all WGs ========
    {
      const u16* z0p = z0bf + prv*16384;
      const u16* ab = ((wv < 2) ? attc : z0p) + r*1024 + (wv & 1)*512 + q*8;
      f32x4 acc = tile_gemm(lw0 + lwoff, ab);
      #pragma unroll
      for (int rr = 0; rr < 4; ++rr) gex[wv][q*4+rr][r] = acc[rr];
      __syncthreads();
      if (tid < 64){
        int b = tid >> 2, dd = tid & 3, d = dg16 + sub4 + dd;
        float g[4];
        #pragma unroll
        for (int gi = 0; gi < 4; ++gi)
          g[gi] = gex[0][b][gi*4+dd] + gex[1][b][gi*4+dd]
                + gex[2][b][gi*4+dd] + gex[3][b][gi*4+dd]
                + b2f(gey[((size_t)b*NOL + t)*4096 + gi*1024 + d]);
        float cn = sigf(g[1])*c0r + sigf(g[0])*tanhf(g[2]);
        float zn = sigf(g[3])*tanhf(cn);
        c0r = cn;
        float zn2 = __shfl_down(zn, 1);
        if ((tid & 1) == 0){
          u32 pk = (u32)f2b(zn) | ((u32)f2b(zn2) << 16);
          coh_stu((u32*)(z0bf + cur*16384 + b*1024 + d), pk);
        }
      }
    }
    gbar(bars, go, slot++);
  }
}

// ---------------- per-row log_softmax + NLL + argmax (bf16 logits) ----------------
__global__ __launch_bounds__(256) void loss_kernel(
    const u16* __restrict__ logits, const int* __restrict__ ys, float* __restrict__ accum){
  int row = blockIdx.x;
  int tid = threadIdx.x;
  const u16* lr = logits + (size_t)row * NO;
  __shared__ float sv[256];
  __shared__ int   si[256];
  float mx = -INFINITY; int mi = 0;
  for (int n = tid; n < NO; n += 256){
    float v = b2f(lr[n]);
    if (v > mx){ mx = v; mi = n; }
  }
  sv[tid] = mx; si[tid] = mi;
  __syncthreads();
  for (int s=128; s>0; s>>=1){
    if (tid < s){
      if (sv[tid+s] > sv[tid] || (sv[tid+s]==sv[tid] && si[tid+s] < si[tid])){
        sv[tid] = sv[tid+s]; si[tid] = si[tid+s];
      }
    }
    __syncthreads();
  }
  float gmx = sv[0]; int gmi = si[0];
  __syncthreads();
  float ps = 0.0f;
  for (int n = tid; n < NO; n += 256) ps += expf(b2f(lr[n])-gmx);
  sv[tid] = ps;
  __syncthreads();
  for (int s=128; s>0; s>>=1){ if (tid<s) sv[tid] += sv[tid+s]; __syncthreads(); }
  if (tid==0){
    int b = row / NOL, l = row - b*NOL;
    int label = (l < NL) ? ys[b*NL + l] : TOK_EOS;
    float lse = gmx + logf(sv[0]);
    float nll = lse - b2f(lr[label]);
    atomicAdd(&accum[0], nll);
    atomicAdd(&accum[1], (gmi==label) ? 1.0f : 0.0f);
  }
}

__global__ void finalize_kernel(const float* __restrict__ accum, float* __restrict__ out){
  out[0] = accum[0] / (float)NROWS * (float)(NOL-1);
  out[1] = accum[1] / (float)NROWS;
}

extern "C" void kernel_launch(void* const* d_in, const int* in_sizes, int n_in,
                              void* d_out, int out_size, void* d_ws, size_t ws_size,
                              hipStream_t stream){
  const float* hpad  = (const float*)d_in[0];
  const int*   hlen  = (const int*)  d_in[1];
  const int*   ys    = (const int*)  d_in[2];
  const float* embed = (const float*)d_in[3];
  const float* Wenc  = (const float*)d_in[4];
  const float* Wdec  = (const float*)d_in[5];
  const float* Wih0  = (const float*)d_in[6];
  const float* Whh0  = (const float*)d_in[7];
  const float* bih0  = (const float*)d_in[8];
  const float* bhh0  = (const float*)d_in[9];
  const float* Wih1  = (const float*)d_in[10];
  const float* Whh1  = (const float*)d_in[11];
  const float* bih1  = (const float*)d_in[12];
  const float* bhh1  = (const float*)d_in[13];
  const float* Wout  = (const float*)d_in[14];
  const float* bout  = (const float*)d_in[15];
  float* out = (float*)d_out;

  char* ws = (char*)d_ws;
  size_t cur = 0;
  auto alloc = [&](size_t bytes) -> char* {
    char* p = ws + cur;
    cur += (bytes + 255) & ~(size_t)255;
    return p;
  };
  u16*   pre_bf   = (u16*)  alloc(16777216);   // [8192][1024]
  u16*   hpadT    = (u16*)  alloc(16777216);   // [16][1024][512]
  u16*   w0c      = (u16*)  alloc(8388608);    // Wih0[:,1024:]
  u16*   wh0      = (u16*)  alloc(8388608);
  u16*   w1c      = (u16*)  alloc(8388608);
  u16*   wh1      = (u16*)  alloc(8388608);
  u16*   wdecT    = (u16*)  alloc(2097152);    // [1024][1024]
  u16*   wencT    = (u16*)  alloc(2097152);    // [1024][1024]
  u16*   woutT    = (u16*)  alloc(20578304);   // [10048][1024]
  u16*   gey      = (u16*)  alloc(16908288);   // [2064][4096]
  u16*   zallb    = (u16*)  alloc(4325376);    // [2112][1024]
  u16*   logits   = (u16*)  alloc(41280000);   // [2064][10000]
  float* dqf      = (float*)alloc(65536);
  float* esc      = (float*)alloc(32768);
  u16*   attc     = (u16*)  alloc(32768);
  float* bias1    = (float*)alloc(16384);
  // ---- zeroed region (contiguous) ----
  u32*   bars     = (u32*)  alloc(2560);       // slots 0..516, go at [600]
  u16*   z0bf     = (u16*)  alloc(65536);      // [2][16][1024]
  u16*   z1bf     = (u16*)  alloc(65536);
  float* accum    = (float*)alloc(128);
  // zero bytes = 2560 + 65536 + 65536 + 128 = 133760 -> 8360 uint4
  zero4_kernel<<<33, 256, 0, stream>>>((uint4*)bars, 8360);

  tcvt_kernel<<<dim3(32,32),  256, 0, stream>>>(Wenc, 1024, 1024, wencT);
  tcvt_kernel<<<dim3(32,32),  256, 0, stream>>>(Wdec, 1024, 1024, wdecT);
  tcvt_kernel<<<dim3(313,32), 256, 0, stream>>>(Wout, 1024, NO,   woutT);
  cvt_nk_kernel<<<4096, 256, 0, stream>>>(Wih0, 2048, 1024, w0c);
  cvt_nk_kernel<<<4096, 256, 0, stream>>>(Whh0, 1024, 0, wh0);
  cvt_nk_kernel<<<4096, 256, 0, stream>>>(Wih1, 1024, 0, w1c);
  cvt_nk_kernel<<<4096, 256, 0, stream>>>(Whh1, 1024, 0, wh1);
  hpadT_kernel<<<dim3(32,16,16), 256, 0, stream>>>(hpad, hlen, hpadT);
  bias_add_kernel<<<16, 256, 0, stream>>>(bih1, bhh1, bias1);
  preenc_mfma<<<dim3(128,16), 256, 0, stream>>>(hpad, hlen, wencT, pre_bf);
  gey_mfma<<<dim3(33,64), 256, 0, stream>>>(ys, embed, Wih0, bih0, bhh0, gey);

  hipFuncSetAttribute((const void*)seq_kernel,
                      hipFuncAttributeMaxDynamicSharedMemorySize, 131072);
  seq_kernel<<<NBLK, 256, 131072, stream>>>(pre_bf, hpadT, w0c, wh0, w1c, wh1,
                                            wdecT, gey, bias1, hlen, dqf, esc, attc,
                                            z0bf, z1bf, zallb, bars);

  logits_mfma<<<dim3(33,157), 256, 0, stream>>>(zallb, woutT, bout, logits);
  loss_kernel<<<NROWS, 256, 0, stream>>>(logits, ys, accum);
  finalize_kernel<<<1, 1, 0, stream>>>(accum, out);
}

// Round 5
// 6180.897 us; speedup vs baseline: 4.8971x; 1.2501x over previous
//
#include <hip/hip_runtime.h>
#include <math.h>

#define NB 16
#define NT 512
#define NE 1024
#define ND 1024
#define NA 1024
#define NO 10000
#define NL 128
#define NOL 129
#define NROWS (NB*NOL)   /* 2064 */
#define TOK_SOS 9999
#define TOK_EOS 9999
#define NBLK 256

typedef unsigned short u16;
typedef unsigned int u32;
typedef __bf16 bf16x8 __attribute__((ext_vector_type(8)));
typedef float f32x4 __attribute__((ext_vector_type(4)));
typedef unsigned short u16x8 __attribute__((ext_vector_type(8)));
typedef unsigned short u16x4 __attribute__((ext_vector_type(4)));

__device__ __forceinline__ float sigf(float x){ return 1.0f/(1.0f+expf(-x)); }
__device__ __forceinline__ float b2f(u16 s){
  union { u32 i; float f; } u; u.i = ((u32)s) << 16; return u.f;
}
__device__ __forceinline__ u16 f2b(float f){
  union { float f; u32 i; } u; u.f = f;
  u32 r = u.i + 0x7FFFu + ((u.i >> 16) & 1u);
  return (u16)(r >> 16);
}
__device__ __forceinline__ bf16x8 cvt8(float4 a, float4 b){
  union { u16 u[8]; bf16x8 v; } c;
  c.u[0]=f2b(a.x); c.u[1]=f2b(a.y); c.u[2]=f2b(a.z); c.u[3]=f2b(a.w);
  c.u[4]=f2b(b.x); c.u[5]=f2b(b.y); c.u[6]=f2b(b.z); c.u[7]=f2b(b.w);
  return c.v;
}
__device__ __forceinline__ bf16x8 zero8(){
  union { u16 u[8]; bf16x8 v; } c;
  #pragma unroll
  for (int i=0;i<8;++i) c.u[i]=0;
  return c.v;
}

// ---- coherent (cache-bypassing, relaxed) helpers ----
__device__ __forceinline__ float coh_ldf(const float* p){
  return __hip_atomic_load((float*)p, __ATOMIC_RELAXED, __HIP_MEMORY_SCOPE_AGENT);
}
__device__ __forceinline__ void coh_stf(float* p, float v){
  __hip_atomic_store(p, v, __ATOMIC_RELAXED, __HIP_MEMORY_SCOPE_AGENT);
}
__device__ __forceinline__ u32 coh_ldu(const u32* p){
  return __hip_atomic_load((u32*)p, __ATOMIC_RELAXED, __HIP_MEMORY_SCOPE_AGENT);
}
__device__ __forceinline__ void coh_stu(u32* p, u32 v){
  __hip_atomic_store(p, v, __ATOMIC_RELAXED, __HIP_MEMORY_SCOPE_AGENT);
}
__device__ __forceinline__ bf16x8 coh_ld8h(const u16* p){
  const u32* q = (const u32*)p;
  union { u32 u[4]; bf16x8 b; } c;
  c.u[0] = coh_ldu(q+0); c.u[1] = coh_ldu(q+1);
  c.u[2] = coh_ldu(q+2); c.u[3] = coh_ldu(q+3);
  return c.b;
}
__device__ __forceinline__ float dot8(bf16x8 a, bf16x8 b){
  float s = 0.f;
  #pragma unroll
  for (int j=0;j<8;++j) s += (float)a[j]*(float)b[j];
  return s;
}

// ---------------- zero ----------------
__global__ void zero4_kernel(uint4* __restrict__ p, int n){
  int i = blockIdx.x*256 + threadIdx.x;
  if (i < n) p[i] = make_uint4(0,0,0,0);
}

// ---------------- f32 [4096][ld] (col slice) -> bf16 [4096][1024] ----------------
__global__ __launch_bounds__(256) void cvt_nk_kernel(
    const float* __restrict__ src, int ld, int off, u16* __restrict__ dst){
  int i = (blockIdx.x*256 + threadIdx.x)*4;
  int row = i >> 10, col = i & 1023;
  float4 v = *(const float4*)(src + (size_t)row*ld + off + col);
  u16x4 o = { f2b(v.x), f2b(v.y), f2b(v.z), f2b(v.w) };
  *(u16x4*)(dst + i) = o;
}

// ---------------- transpose-convert: src f32 [R][C] -> dst bf16 [C'][R] ----------------
__global__ __launch_bounds__(256) void tcvt_kernel(
    const float* __restrict__ src, int R, int C, u16* __restrict__ dst){
  __shared__ float tile[32][33];
  const int c0 = blockIdx.x*32, r0 = blockIdx.y*32;
  const int tx = threadIdx.x & 31, ty = threadIdx.x >> 5;
  #pragma unroll
  for (int k = 0; k < 4; ++k){
    int rr = ty + k*8;
    int c = c0 + tx;
    float v = (c < C) ? src[(size_t)(r0+rr)*C + c] : 0.0f;
    tile[rr][tx] = v;
  }
  __syncthreads();
  #pragma unroll
  for (int k = 0; k < 4; ++k){
    int cc = ty + k*8;
    dst[(size_t)(c0+cc)*R + r0 + tx] = f2b(tile[tx][cc]);
  }
}

// ---------------- hpad [16][512][1024] f32 -> masked bf16 transposed [16][1024][512] -------
__global__ __launch_bounds__(256) void hpadT_kernel(
    const float* __restrict__ hpad, const int* __restrict__ hlen, u16* __restrict__ dst){
  __shared__ float tile[32][33];
  const int e0 = blockIdx.x*32, t0 = blockIdx.y*32, b = blockIdx.z;
  const int tx = threadIdx.x & 31, ty = threadIdx.x >> 5;
  const int len = hlen[b];
  #pragma unroll
  for (int k = 0; k < 4; ++k){
    int r = ty + k*8;
    tile[r][tx] = hpad[((size_t)b*512 + t0 + r)*1024 + e0 + tx];
  }
  __syncthreads();
  #pragma unroll
  for (int k = 0; k < 4; ++k){
    int el = ty + k*8;
    float m = (t0 + tx < len) ? 1.0f : 0.0f;
    dst[((size_t)b*1024 + e0 + el)*512 + t0 + tx] = f2b(tile[tx][el]*m);
  }
}

// ---------------- bias1 = bih1 + bhh1 ----------------
__global__ void bias_add_kernel(const float* __restrict__ a, const float* __restrict__ b,
                                float* __restrict__ o){
  int i = blockIdx.x*256 + threadIdx.x;
  if (i < 4096) o[i] = a[i] + b[i];
}

// ---------------- pre_enc = tanh(mask(hpad) @ Wenc) via MFMA -> bf16 [8192][1024] ----------
__global__ __launch_bounds__(256) void preenc_mfma(
    const float* __restrict__ hpad, const int* __restrict__ hlen,
    const u16* __restrict__ wencT, u16* __restrict__ pre){
  const int m0 = blockIdx.x*64, n0 = blockIdx.y*64;
  const int tid = threadIdx.x, lane = tid & 63, wv = tid >> 6;
  const int r = lane & 15, q = lane >> 4;
  const int ar = m0 + wv*16 + r;
  const bool on = (ar & 511) < hlen[ar >> 9];
  const float* ap = hpad + (size_t)ar*1024 + q*8;
  f32x4 acc[4] = {{0,0,0,0},{0,0,0,0},{0,0,0,0},{0,0,0,0}};
  for (int kt = 0; kt < 32; ++kt){
    bf16x8 a;
    if (on){
      float4 v0 = *(const float4*)(ap + kt*32);
      float4 v1 = *(const float4*)(ap + kt*32 + 4);
      a = cvt8(v0, v1);
    } else a = zero8();
    #pragma unroll
    for (int s = 0; s < 4; ++s){
      const u16* bp = wencT + (size_t)(n0 + s*16 + r)*1024 + kt*32 + q*8;
      acc[s] = __builtin_amdgcn_mfma_f32_16x16x32_bf16(a, *(const bf16x8*)bp, acc[s], 0,0,0);
    }
  }
  #pragma unroll
  for (int s = 0; s < 4; ++s)
    #pragma unroll
    for (int rr = 0; rr < 4; ++rr){
      int row = m0 + wv*16 + q*4 + rr, col = n0 + s*16 + r;
      pre[(size_t)row*1024 + col] = f2b(tanhf(acc[s][rr]));
    }
}

// ---------------- gey = embed[ys_in] @ Wih0[:,0:1024]^T + bih0 + bhh0 via MFMA -> bf16 -----
__global__ __launch_bounds__(256) void gey_mfma(
    const int* __restrict__ ys, const float* __restrict__ embed,
    const float* __restrict__ Wih0, const float* __restrict__ bih0,
    const float* __restrict__ bhh0, u16* __restrict__ gey){
  const int m0 = blockIdx.x*64, n0 = blockIdx.y*64;
  const int tid = threadIdx.x, lane = tid & 63, wv = tid >> 6;
  const int r = lane & 15, q = lane >> 4;
  const int ar = m0 + wv*16 + r;
  int tok = 0;
  if (ar < NROWS){
    int bb = ar / NOL, l = ar - bb*NOL;
    tok = (l==0) ? TOK_SOS : ys[bb*NL + l - 1];
  }
  const float* ap = embed + (size_t)tok*1024 + q*8;
  f32x4 acc[4] = {{0,0,0,0},{0,0,0,0},{0,0,0,0},{0,0,0,0}};
  for (int kt = 0; kt < 32; ++kt){
    float4 v0 = *(const float4*)(ap + kt*32);
    float4 v1 = *(const float4*)(ap + kt*32 + 4);
    bf16x8 a = cvt8(v0, v1);
    #pragma unroll
    for (int s = 0; s < 4; ++s){
      const float* bp = Wih0 + (size_t)(n0 + s*16 + r)*2048 + kt*32 + q*8;
      float4 w0 = *(const float4*)(bp);
      float4 w1 = *(const float4*)(bp + 4);
      acc[s] = __builtin_amdgcn_mfma_f32_16x16x32_bf16(a, cvt8(w0,w1), acc[s], 0,0,0);
    }
  }
  #pragma unroll
  for (int s = 0; s < 4; ++s)
    #pragma unroll
    for (int rr = 0; rr < 4; ++rr){
      int row = m0 + wv*16 + q*4 + rr, col = n0 + s*16 + r;
      if (row < NROWS)
        gey[(size_t)row*4096 + col] = f2b(acc[s][rr] + bih0[col] + bhh0[col]);
    }
}

// ---------------- logits = zallb @ woutT^T + bout via MFMA -> bf16 [2064][10000] -----------
__global__ __launch_bounds__(256) void logits_mfma(
    const u16* __restrict__ zallb, const u16* __restrict__ woutT,
    const float* __restrict__ bout, u16* __restrict__ logits){
  const int m0 = blockIdx.x*64, n0 = blockIdx.y*64;
  const int tid = threadIdx.x, lane = tid & 63, wv = tid >> 6;
  const int r = lane & 15, q = lane >> 4;
  const int ar = m0 + wv*16 + r;
  const u16* ap = zallb + (size_t)ar*1024 + q*8;
  f32x4 acc[4] = {{0,0,0,0},{0,0,0,0},{0,0,0,0},{0,0,0,0}};
  for (int kt = 0; kt < 32; ++kt){
    bf16x8 a = *(const bf16x8*)(ap + kt*32);
    #pragma unroll
    for (int s = 0; s < 4; ++s){
      const u16* bp = woutT + (size_t)(n0 + s*16 + r)*1024 + kt*32 + q*8;
      acc[s] = __builtin_amdgcn_mfma_f32_16x16x32_bf16(a, *(const bf16x8*)bp, acc[s], 0,0,0);
    }
  }
  #pragma unroll
  for (int s = 0; s < 4; ++s)
    #pragma unroll
    for (int rr = 0; rr < 4; ++rr){
      int row = m0 + wv*16 + q*4 + rr, col = n0 + s*16 + r;
      if (row < NROWS && col < NO)
        logits[(size_t)row*NO + col] = f2b(acc[s][rr] + bout[col]);
    }
}

// ---------------- flag/broadcast grid barrier (no RMW contention) ----------------
// af[w*32] = arrival flag of WG w (w>0); af[0] = broadcast "go" word.
// Entry __syncthreads drains each thread's coherent stores (vmcnt) -> data visible
// before the flag store; all cross-WG data uses relaxed agent ops, so no fences.
__device__ __forceinline__ void gbar(u32* af, int epoch){
  __syncthreads();
  if (blockIdx.x == 0){
    int w = threadIdx.x;
    if (w > 0){
      while (coh_ldu(&af[w << 5]) < (u32)epoch) __builtin_amdgcn_s_sleep(1);
    }
    __syncthreads();
    if (threadIdx.x == 0) coh_stu(&af[0], (u32)epoch);
  } else {
    if (threadIdx.x == 0){
      coh_stu(&af[blockIdx.x << 5], (u32)epoch);
      while (coh_ldu(&af[0]) < (u32)epoch) __builtin_amdgcn_s_sleep(1);
    }
    __syncthreads();
  }
}

// one 16x16 output tile, K=512 slice per wave, weights from LDS
__device__ __forceinline__ f32x4 tile_gemm(const u16* lw, const u16* ab){
  f32x4 acc = {0.f,0.f,0.f,0.f};
  #pragma unroll
  for (int kt = 0; kt < 16; ++kt){
    bf16x8 a = coh_ld8h(ab + kt*32);
    bf16x8 b = *(const bf16x8*)(lw + kt*512);
    acc = __builtin_amdgcn_mfma_f32_16x16x32_bf16(a, b, acc, 0, 0, 0);
  }
  return acc;
}

// ---------------- persistent sequential kernel: 256 WGs, weights LDS-resident ----------------
__global__ __launch_bounds__(256, 1) void seq_kernel(
    const u16* __restrict__ pre,    // [8192][1024] bf16
    const u16* __restrict__ hpadT,  // [16][1024][512] bf16 masked
    const u16* __restrict__ w0c,    // [4096][1024] Wih0[:,1024:] bf16
    const u16* __restrict__ wh0,    // [4096][1024]
    const u16* __restrict__ w1c,    // [4096][1024]
    const u16* __restrict__ wh1,    // [4096][1024]
    const u16* __restrict__ wdecT,  // [1024 n][1024 k] bf16
    const u16* __restrict__ gey,    // [2064][4096] bf16
    const float* __restrict__ bias1,// [4096]
    const int* __restrict__ hlen,
    float* dqf,                     // [16][1024] f32   (coherent)
    float* esc,                     // [8192] f32       (coherent)
    u16* attc,                      // [16][1024] bf16  (coherent)
    u16* z0bf, u16* z1bf,           // [2][16][1024] bf16 ping-pong (coherent)
    u16* zallb,                     // [2112][1024] bf16
    u32* af)
{
  const int wg = blockIdx.x, tid = threadIdx.x;
  const int lane = tid & 63, wv = tid >> 6;
  const int r = lane & 15, q = lane >> 4;

  extern __shared__ __align__(16) u16 dynlds[];
  u16* lw1 = dynlds;            // [kb 0..255][c 0..15][8] = 64 KB
  u16* lw0 = dynlds + 32768;    // 64 KB
  __shared__ float sred[256];
  __shared__ float sw[512];
  __shared__ float spart[4][64];
  __shared__ float gex[4][16][16];
  __shared__ float sdq[16*16*4];

  const int dg16 = (wg & 63)*16, sub4 = (wg >> 6)*4;

  // ---- stage weights into LDS (once); lane-consecutive LDS writes ----
  {
    #pragma unroll
    for (int it = 0; it < 16; ++it){
      int m = tid + it*256;          // m = kb*16 + c
      int kb = m >> 4, c = m & 15;
      int k0 = kb*8;
      int gi = c >> 2;
      int d  = dg16 + sub4 + (c & 3);
      size_t gr = (size_t)(gi*1024 + d)*1024;
      const u16* s1 = (k0 < 1024) ? (w1c + gr + k0) : (wh1 + gr + k0 - 1024);
      const u16* s0 = (k0 < 1024) ? (w0c + gr + k0) : (wh0 + gr + k0 - 1024);
      *(u16x8*)(lw1 + (m << 3)) = *(const u16x8*)s1;
      *(u16x8*)(lw0 + (m << 3)) = *(const u16x8*)s0;
    }
  }
  __syncthreads();

  float c0r = 0.f, c1r = 0.f;    // cell states, owned by tid<64 (b=tid>>2, dd=tid&3)
  int epoch = 1;
  const int lwoff = ((wv*64 + q)*16 + r) << 3;

  for (int t = 0; t <= NOL; ++t){
    const int cur = t & 1, prv = cur ^ 1;

    // ======== Phase A: gemm1+cell1(t-1) + dq(t), all WGs ========
    if (t >= 1){
      const int s = t - 1;
      const u16* z0p = z0bf + prv*16384;
      const u16* z1p = z1bf + cur*16384;
      const u16* ab = ((wv < 2) ? z0p : z1p) + r*1024 + (wv & 1)*512 + q*8;
      f32x4 acc = tile_gemm(lw1 + lwoff, ab);
      #pragma unroll
      for (int rr = 0; rr < 4; ++rr) gex[wv][q*4+rr][r] = acc[rr];
      __syncthreads();
      if (tid < 64){
        int b = tid >> 2, dd = tid & 3, d = dg16 + sub4 + dd;
        float g[4];
        #pragma unroll
        for (int gi = 0; gi < 4; ++gi)
          g[gi] = gex[0][b][gi*4+dd] + gex[1][b][gi*4+dd]
                + gex[2][b][gi*4+dd] + gex[3][b][gi*4+dd] + bias1[gi*1024 + d];
        float cn = sigf(g[1])*c1r + sigf(g[0])*tanhf(g[2]);
        float zn = sigf(g[3])*tanhf(cn);
        c1r = cn;
        float zn2 = __shfl_down(zn, 1);
        if ((tid & 1) == 0){
          u32 pk = (u32)f2b(zn) | ((u32)f2b(zn2) << 16);
          *(u32*)(zallb + ((size_t)b*NOL + s)*1024 + d) = pk;
          coh_stu((u32*)(z1bf + prv*16384 + b*1024 + d), pk);
        }
      }
      __syncthreads();
    }
    if (t < NOL){
      // dq: this WG computes n = wg*4 .. wg*4+3 for all 16 batches
      const u16* z0p = z0bf + prv*16384;
      const int b = tid & 15, ks = tid >> 4;
      float a4[4] = {0.f,0.f,0.f,0.f};
      #pragma unroll
      for (int i = 0; i < 8; ++i){
        bf16x8 za = coh_ld8h(z0p + b*1024 + ks*64 + i*8);
        #pragma unroll
        for (int nn = 0; nn < 4; ++nn){
          bf16x8 wb = *(const bf16x8*)(wdecT + (size_t)(wg*4+nn)*1024 + ks*64 + i*8);
          a4[nn] += dot8(za, wb);
        }
      }
      #pragma unroll
      for (int nn = 0; nn < 4; ++nn) sdq[(ks*16 + b)*4 + nn] = a4[nn];
      __syncthreads();
      if (tid < 64){
        int b2 = tid >> 2, nn = tid & 3;
        float s2 = 0.f;
        #pragma unroll
        for (int ks2 = 0; ks2 < 16; ++ks2) s2 += sdq[(ks2*16 + b2)*4 + nn];
        coh_stf(dqf + b2*1024 + wg*4 + nn, tanhf(s2));
      }
    }
    gbar(af, epoch++);
    if (t == NOL) break;

    // ======== Phase B: escore = 2 * pre . dq  (32 rows per WG) ========
    {
      const int rbase = wg*32 + wv*8;
      const int b = (wg*32) >> 9;
      float qv[16];
      const float* dqb = dqf + b*1024 + lane*16;
      #pragma unroll
      for (int j = 0; j < 16; ++j) qv[j] = coh_ldf(dqb + j);
      #pragma unroll
      for (int rr = 0; rr < 8; ++rr){
        const u16* pr = pre + (size_t)(rbase+rr)*1024 + lane*16;
        u16x8 p0 = *(const u16x8*)(pr);
        u16x8 p1 = *(const u16x8*)(pr+8);
        float acc = 0.f;
        #pragma unroll
        for (int j = 0; j < 8; ++j){
          acc += b2f(p0[j])*qv[j];
          acc += b2f(p1[j])*qv[8+j];
        }
        #pragma unroll
        for (int off = 32; off > 0; off >>= 1) acc += __shfl_xor(acc, off, 64);
        if (lane == 0) coh_stf(&esc[rbase+rr], 2.0f*acc);
      }
    }
    gbar(af, epoch++);

    // ======== Phase C: softmax + att_c (b = wg>>4, 64-col e-slice) ========
    {
      const int b = wg >> 4, ec = wg & 15;
      const int len = hlen[b];
      float e0 = (tid < len)     ? coh_ldf(&esc[b*512 + tid])       : -INFINITY;
      float e1 = (tid+256 < len) ? coh_ldf(&esc[b*512 + tid + 256]) : -INFINITY;
      sred[tid] = fmaxf(e0, e1);
      __syncthreads();
      #pragma unroll
      for (int s2 = 128; s2 > 0; s2 >>= 1){
        if (tid < s2) sred[tid] = fmaxf(sred[tid], sred[tid+s2]);
        __syncthreads();
      }
      float mx = sred[0];
      __syncthreads();
      float p0 = (tid < len)     ? expf(e0 - mx) : 0.0f;
      float p1 = (tid+256 < len) ? expf(e1 - mx) : 0.0f;
      sred[tid] = p0 + p1;
      __syncthreads();
      #pragma unroll
      for (int s2 = 128; s2 > 0; s2 >>= 1){
        if (tid < s2) sred[tid] += sred[tid+s2];
        __syncthreads();
      }
      float inv = 1.0f/sred[0];
      sw[tid] = p0*inv; sw[tid+256] = p1*inv;
      __syncthreads();
      const int el = tid & 63, th = tid >> 6;
      const u16* hp = hpadT + ((size_t)b*1024 + ec*64 + el)*512 + th*128;
      float acc = 0.f;
      #pragma unroll
      for (int i = 0; i < 16; ++i){
        u16x8 v = *(const u16x8*)(hp + i*8);
        #pragma unroll
        for (int j = 0; j < 8; ++j) acc += sw[th*128 + i*8 + j]*b2f(v[j]);
      }
      spart[th][el] = acc;
      __syncthreads();
      if (tid < 64){
        float s2 = spart[0][tid]+spart[1][tid]+spart[2][tid]+spart[3][tid];
        float s2n = __shfl_down(s2, 1);
        if ((tid & 1) == 0){
          u32 pk = (u32)f2b(s2) | ((u32)f2b(s2n) << 16);
          coh_stu((u32*)(attc + b*1024 + ec*64 + tid), pk);
        }
      }
    }
    gbar(af, epoch++);

    // ======== Phase D: gemm0 + cell0(t), all WGs ========
    {
      const u16* z0p = z0bf + prv*16384;
      const u16* ab = ((wv < 2) ? attc : z0p) + r*1024 + (wv & 1)*512 + q*8;
      f32x4 acc = tile_gemm(lw0 + lwoff, ab);
      #pragma unroll
      for (int rr = 0; rr < 4; ++rr) gex[wv][q*4+rr][r] = acc[rr];
      __syncthreads();
      if (tid < 64){
        int b = tid >> 2, dd = tid & 3, d = dg16 + sub4 + dd;
        float g[4];
        #pragma unroll
        for (int gi = 0; gi < 4; ++gi)
          g[gi] = gex[0][b][gi*4+dd] + gex[1][b][gi*4+dd]
                + gex[2][b][gi*4+dd] + gex[3][b][gi*4+dd]
                + b2f(gey[((size_t)b*NOL + t)*4096 + gi*1024 + d]);
        float cn = sigf(g[1])*c0r + sigf(g[0])*tanhf(g[2]);
        float zn = sigf(g[3])*tanhf(cn);
        c0r = cn;
        float zn2 = __shfl_down(zn, 1);
        if ((tid & 1) == 0){
          u32 pk = (u32)f2b(zn) | ((u32)f2b(zn2) << 16);
          coh_stu((u32*)(z0bf + cur*16384 + b*1024 + d), pk);
        }
      }
    }
    gbar(af, epoch++);
  }
}

// ---------------- per-row log_softmax + NLL + argmax (bf16 logits) ----------------
__global__ __launch_bounds__(256) void loss_kernel(
    const u16* __restrict__ logits, const int* __restrict__ ys, float* __restrict__ accum){
  int row = blockIdx.x;
  int tid = threadIdx.x;
  const u16* lr = logits + (size_t)row * NO;
  __shared__ float sv[256];
  __shared__ int   si[256];
  float mx = -INFINITY; int mi = 0;
  for (int n = tid; n < NO; n += 256){
    float v = b2f(lr[n]);
    if (v > mx){ mx = v; mi = n; }
  }
  sv[tid] = mx; si[tid] = mi;
  __syncthreads();
  for (int s=128; s>0; s>>=1){
    if (tid < s){
      if (sv[tid+s] > sv[tid] || (sv[tid+s]==sv[tid] && si[tid+s] < si[tid])){
        sv[tid] = sv[tid+s]; si[tid] = si[tid+s];
      }
    }
    __syncthreads();
  }
  float gmx = sv[0]; int gmi = si[0];
  __syncthreads();
  float ps = 0.0f;
  for (int n = tid; n < NO; n += 256) ps += expf(b2f(lr[n])-gmx);
  sv[tid] = ps;
  __syncthreads();
  for (int s=128; s>0; s>>=1){ if (tid<s) sv[tid] += sv[tid+s]; __syncthreads(); }
  if (tid==0){
    int b = row / NOL, l = row - b*NOL;
    int label = (l < NL) ? ys[b*NL + l] : TOK_EOS;
    float lse = gmx + logf(sv[0]);
    float nll = lse - b2f(lr[label]);
    atomicAdd(&accum[0], nll);
    atomicAdd(&accum[1], (gmi==label) ? 1.0f : 0.0f);
  }
}

__global__ void finalize_kernel(const float* __restrict__ accum, float* __restrict__ out){
  out[0] = accum[0] / (float)NROWS * (float)(NOL-1);
  out[1] = accum[1] / (float)NROWS;
}

extern "C" void kernel_launch(void* const* d_in, const int* in_sizes, int n_in,
                              void* d_out, int out_size, void* d_ws, size_t ws_size,
                              hipStream_t stream){
  const float* hpad  = (const float*)d_in[0];
  const int*   hlen  = (const int*)  d_in[1];
  const int*   ys    = (const int*)  d_in[2];
  const float* embed = (const float*)d_in[3];
  const float* Wenc  = (const float*)d_in[4];
  const float* Wdec  = (const float*)d_in[5];
  const float* Wih0  = (const float*)d_in[6];
  const float* Whh0  = (const float*)d_in[7];
  const float* bih0  = (const float*)d_in[8];
  const float* bhh0  = (const float*)d_in[9];
  const float* Wih1  = (const float*)d_in[10];
  const float* Whh1  = (const float*)d_in[11];
  const float* bih1  = (const float*)d_in[12];
  const float* bhh1  = (const float*)d_in[13];
  const float* Wout  = (const float*)d_in[14];
  const float* bout  = (const float*)d_in[15];
  float* out = (float*)d_out;

  char* ws = (char*)d_ws;
  size_t cur = 0;
  auto alloc = [&](size_t bytes) -> char* {
    char* p = ws + cur;
    cur += (bytes + 255) & ~(size_t)255;
    return p;
  };
  u16*   pre_bf   = (u16*)  alloc(16777216);   // [8192][1024]
  u16*   hpadT    = (u16*)  alloc(16777216);   // [16][1024][512]
  u16*   w0c      = (u16*)  alloc(8388608);    // Wih0[:,1024:]
  u16*   wh0      = (u16*)  alloc(8388608);
  u16*   w1c      = (u16*)  alloc(8388608);
  u16*   wh1      = (u16*)  alloc(8388608);
  u16*   wdecT    = (u16*)  alloc(2097152);    // [1024][1024]
  u16*   wencT    = (u16*)  alloc(2097152);    // [1024][1024]
  u16*   woutT    = (u16*)  alloc(20578304);   // [10048][1024]
  u16*   gey      = (u16*)  alloc(16908288);   // [2064][4096]
  u16*   zallb    = (u16*)  alloc(4325376);    // [2112][1024]
  u16*   logits   = (u16*)  alloc(41280000);   // [2064][10000]
  float* dqf      = (float*)alloc(65536);
  float* esc      = (float*)alloc(32768);
  u16*   attc     = (u16*)  alloc(32768);
  float* bias1    = (float*)alloc(16384);
  // ---- zeroed region (contiguous) ----
  u32*   af       = (u32*)  alloc(32768);      // 256 WGs x 128B; af[0] = go word
  u16*   z0bf     = (u16*)  alloc(65536);      // [2][16][1024]
  u16*   z1bf     = (u16*)  alloc(65536);
  float* accum    = (float*)alloc(128);
  // zero bytes = 32768 + 65536 + 65536 + 128 = 163968 -> 10248 uint4
  zero4_kernel<<<41, 256, 0, stream>>>((uint4*)af, 10248);

  tcvt_kernel<<<dim3(32,32),  256, 0, stream>>>(Wenc, 1024, 1024, wencT);
  tcvt_kernel<<<dim3(32,32),  256, 0, stream>>>(Wdec, 1024, 1024, wdecT);
  tcvt_kernel<<<dim3(313,32), 256, 0, stream>>>(Wout, 1024, NO,   woutT);
  cvt_nk_kernel<<<4096, 256, 0, stream>>>(Wih0, 2048, 1024, w0c);
  cvt_nk_kernel<<<4096, 256, 0, stream>>>(Whh0, 1024, 0, wh0);
  cvt_nk_kernel<<<4096, 256, 0, stream>>>(Wih1, 1024, 0, w1c);
  cvt_nk_kernel<<<4096, 256, 0, stream>>>(Whh1, 1024, 0, wh1);
  hpadT_kernel<<<dim3(32,16,16), 256, 0, stream>>>(hpad, hlen, hpadT);
  bias_add_kernel<<<16, 256, 0, stream>>>(bih1, bhh1, bias1);
  preenc_mfma<<<dim3(128,16), 256, 0, stream>>>(hpad, hlen, wencT, pre_bf);
  gey_mfma<<<dim3(33,64), 256, 0, stream>>>(ys, embed, Wih0, bih0, bhh0, gey);

  hipFuncSetAttribute((const void*)seq_kernel,
                      hipFuncAttributeMaxDynamicSharedMemorySize, 131072);
  seq_kernel<<<NBLK, 256, 131072, stream>>>(pre_bf, hpadT, w0c, wh0, w1c, wh1,
                                            wdecT, gey, bias1, hlen, dqf, esc, attc,
                                            z0bf, z1bf, zallb, af);

  logits_mfma<<<dim3(33,157), 256, 0, stream>>>(zallb, woutT, bout, logits);
  loss_kernel<<<NROWS, 256, 0, stream>>>(logits, ys, accum);
  finalize_kernel<<<1, 1, 0, stream>>>(accum, out);
}